// Round 7
// baseline (2781.323 us; speedup 1.0000x reference)
//
#include <hip/hip_runtime.h>

#define LATENT 64
#define SUB_SHIFT 7
#define SUB_ROWS 128
#define COLBITS 17
#define COL_MASK ((1 << COLBITS) - 1)
#define HIST_BLOCKS 256
#define TILE 8192
#define NSUB_PAD 1024

__device__ __forceinline__ unsigned short f2bf(float f) {
    unsigned u = __float_as_uint(f);
    unsigned r = (u + 0x7FFFu + ((u >> 16) & 1u)) >> 16;   // round-nearest-even
    return (unsigned short)r;
}
__device__ __forceinline__ float bf2f(unsigned short h) {
    return __uint_as_float(((unsigned)h) << 16);
}

// ---------------------------------------------------------------------------
// Kernel A: per-block sub-bucket histogram partials (no global atomics)
// ---------------------------------------------------------------------------
__global__ void subhist_kernel(const int* __restrict__ rows, int* __restrict__ part,
                               int E, int nsub) {
    __shared__ int h[NSUB_PAD];
    int t = threadIdx.x;
    for (int i = t; i < NSUB_PAD; i += blockDim.x) h[i] = 0;
    __syncthreads();
    for (int e = blockIdx.x * blockDim.x + t; e < E; e += gridDim.x * blockDim.x)
        atomicAdd(&h[rows[e] >> SUB_SHIFT], 1);
    __syncthreads();
    for (int i = t; i < nsub; i += blockDim.x) part[blockIdx.x * nsub + i] = h[i];
}

// ---------------------------------------------------------------------------
// Kernel A2: parallel reduction of partials -> tot[s]. One block per sub-bucket.
// ---------------------------------------------------------------------------
__global__ void reduce_partials_kernel(const int* __restrict__ part, int* __restrict__ tot,
                                       int nsub, int nblk) {
    __shared__ int s[256];
    int sidx = blockIdx.x;
    int t = threadIdx.x;
    int acc = 0;
    for (int b = t; b < nblk; b += 256) acc += part[b * nsub + sidx];
    s[t] = acc;
    __syncthreads();
    for (int o = 128; o > 0; o >>= 1) {
        if (t < o) s[t] += s[t + o];
        __syncthreads();
    }
    if (t == 0) tot[sidx] = s[0];
}

// ---------------------------------------------------------------------------
// Kernel B (1 block): exclusive scan of tot -> tstart, stot, gcur
// tstart[s] = excl_prefix(s) + 8*s  (8-payload gap => bins never share a line)
// ---------------------------------------------------------------------------
__global__ void subscan_kernel(const int* __restrict__ tot_in, int* __restrict__ tstart,
                               int* __restrict__ stot, int* __restrict__ gcur, int nsub) {
    __shared__ int tot[NSUB_PAD];
    __shared__ int sc[256];
    int t = threadIdx.x;
    for (int i = t; i < NSUB_PAD; i += 256) tot[i] = (i < nsub) ? tot_in[i] : 0;
    __syncthreads();
    int c0 = tot[4 * t], c1 = tot[4 * t + 1], c2 = tot[4 * t + 2], c3 = tot[4 * t + 3];
    int csum = c0 + c1 + c2 + c3;
    sc[t] = csum;
    __syncthreads();
    for (int o = 1; o < 256; o <<= 1) {
        int u = (t >= o) ? sc[t - o] : 0;
        __syncthreads();
        sc[t] += u;
        __syncthreads();
    }
    int pre = sc[t] - csum;   // exclusive chunk base
    int s0 = 4 * t;
    if (s0 < nsub)     { stot[s0] = c0;     int ts = pre + 8 * s0;       tstart[s0] = ts;     gcur[s0] = ts; }
    pre += c0;
    if (s0 + 1 < nsub) { stot[s0 + 1] = c1; int ts = pre + 8 * (s0 + 1); tstart[s0 + 1] = ts; gcur[s0 + 1] = ts; }
    pre += c1;
    if (s0 + 2 < nsub) { stot[s0 + 2] = c2; int ts = pre + 8 * (s0 + 2); tstart[s0 + 2] = ts; gcur[s0 + 2] = ts; }
    pre += c2;
    if (s0 + 3 < nsub) { stot[s0 + 3] = c3; int ts = pre + 8 * (s0 + 3); tstart[s0 + 3] = ts; gcur[s0 + 3] = ts; }
}

// ---------------------------------------------------------------------------
// x (f32) -> bf16 table, vectorized 4 at a time
// ---------------------------------------------------------------------------
__global__ void conv_bf16_kernel(const float* __restrict__ in,
                                 unsigned short* __restrict__ outb, long long n4) {
    long long i = (long long)blockIdx.x * blockDim.x + threadIdx.x;
    long long stride = (long long)gridDim.x * blockDim.x;
    for (; i < n4; i += stride) {
        float4 f = reinterpret_cast<const float4*>(in)[i];
        ushort4 o;
        o.x = f2bf(f.x); o.y = f2bf(f.y); o.z = f2bf(f.z); o.w = f2bf(f.w);
        reinterpret_cast<ushort4*>(outb)[i] = o;
    }
}

// ---------------------------------------------------------------------------
// Pass 1: tile-local LDS bucket sort, then append contiguous runs to bins.
// ---------------------------------------------------------------------------
__global__ void __launch_bounds__(256, 2) binscatter_kernel(
        const int* __restrict__ rows, const int* __restrict__ cols,
        const float* __restrict__ vals, int* __restrict__ gcur,
        int2* __restrict__ tmp, int E, int nsub) {
    __shared__ int hist[NSUB_PAD];
    __shared__ int base[NSUB_PAD];
    __shared__ int gbase[NSUB_PAD];
    __shared__ int2 stage[TILE];
    __shared__ int sc[256];
    int t = threadIdx.x;
    int tb = blockIdx.x * TILE;
    int tilecnt = E - tb; if (tilecnt > TILE) tilecnt = TILE;

    for (int i = t; i < NSUB_PAD; i += 256) hist[i] = 0;
    __syncthreads();
    #pragma unroll
    for (int k = 0; k < TILE / 256; ++k) {
        int e = tb + k * 256 + t;
        if (e < E) atomicAdd(&hist[rows[e] >> SUB_SHIFT], 1);
    }
    __syncthreads();
    int c0 = hist[4 * t], c1 = hist[4 * t + 1], c2 = hist[4 * t + 2], c3 = hist[4 * t + 3];
    int csum = c0 + c1 + c2 + c3;
    sc[t] = csum;
    __syncthreads();
    for (int o = 1; o < 256; o <<= 1) {
        int u = (t >= o) ? sc[t - o] : 0;
        __syncthreads();
        sc[t] += u;
        __syncthreads();
    }
    int ex = sc[t] - csum;
    base[4 * t] = ex;
    base[4 * t + 1] = ex + c0;
    base[4 * t + 2] = ex + c0 + c1;
    base[4 * t + 3] = ex + c0 + c1 + c2;
    __syncthreads();
    for (int i = t; i < NSUB_PAD; i += 256) hist[i] = 0;
    __syncthreads();
    #pragma unroll
    for (int k = 0; k < TILE / 256; ++k) {
        int e = tb + k * 256 + t;
        if (e < E) {
            int r = rows[e];
            int b = r >> SUB_SHIFT;
            int pos = base[b] + atomicAdd(&hist[b], 1);
            stage[pos] = make_int2(cols[e] | ((r & (SUB_ROWS - 1)) << COLBITS),
                                   __float_as_int(vals[e]));
        }
    }
    __syncthreads();
    for (int i = t; i < nsub; i += 256) {
        int n = hist[i];
        int gb = 0;
        if (n > 0) gb = atomicAdd(&gcur[i], n);
        gbase[i] = gb - base[i];
    }
    __syncthreads();
    for (int p = t; p < tilecnt; p += 256) {
        int lo = 0, hi = nsub;
        while (hi - lo > 1) { int mid = (lo + hi) >> 1; if (base[mid] <= p) lo = mid; else hi = mid; }
        tmp[gbase[lo] + p] = stage[p];
    }
}

// ---------------------------------------------------------------------------
// Fused hop kernels: one block per sub-bucket. Sequential read of the bucket's
// bin-sorted edge slice; gather bf16 operand rows; accumulate f32 into a 32KB
// LDS accumulator acc[128][64] via conflict-free ds_add_f32 (addr = rl*64+lane,
// banks = lane%32 -> 2 lanes/bank, free). No per-row sort, no CSR needed.
// ---------------------------------------------------------------------------

#define HOP_BODY(SRC)                                                                   \
    __shared__ float acc[SUB_ROWS * LATENT];                                            \
    int s = blockIdx.x, t = threadIdx.x;                                                \
    int lane = t & 63, wid = t >> 6;                                                    \
    for (int i = t; i < SUB_ROWS * LATENT; i += 256) acc[i] = 0.f;                      \
    __syncthreads();                                                                    \
    int beg = tstart[s], n = stot[s];                                                   \
    int chunk = (n + 3) >> 2;                                                           \
    int wb = beg + wid * chunk;                                                         \
    int we = wb + chunk;                                                                \
    int lim = beg + n; if (we > lim) we = lim;                                          \
    int i = wb;                                                                         \
    for (; i + 8 <= we; i += 8) {                                                       \
        int2 w0 = tmp[i],     w1 = tmp[i + 1], w2 = tmp[i + 2], w3 = tmp[i + 3];        \
        int2 w4 = tmp[i + 4], w5 = tmp[i + 5], w6 = tmp[i + 6], w7 = tmp[i + 7];        \
        float x0 = bf2f(SRC[(size_t)(w0.x & COL_MASK) * LATENT + lane]);                \
        float x1 = bf2f(SRC[(size_t)(w1.x & COL_MASK) * LATENT + lane]);                \
        float x2 = bf2f(SRC[(size_t)(w2.x & COL_MASK) * LATENT + lane]);                \
        float x3 = bf2f(SRC[(size_t)(w3.x & COL_MASK) * LATENT + lane]);                \
        float x4 = bf2f(SRC[(size_t)(w4.x & COL_MASK) * LATENT + lane]);                \
        float x5 = bf2f(SRC[(size_t)(w5.x & COL_MASK) * LATENT + lane]);                \
        float x6 = bf2f(SRC[(size_t)(w6.x & COL_MASK) * LATENT + lane]);                \
        float x7 = bf2f(SRC[(size_t)(w7.x & COL_MASK) * LATENT + lane]);                \
        atomicAdd(&acc[((w0.x >> COLBITS) & (SUB_ROWS - 1)) * LATENT + lane], __int_as_float(w0.y) * x0); \
        atomicAdd(&acc[((w1.x >> COLBITS) & (SUB_ROWS - 1)) * LATENT + lane], __int_as_float(w1.y) * x1); \
        atomicAdd(&acc[((w2.x >> COLBITS) & (SUB_ROWS - 1)) * LATENT + lane], __int_as_float(w2.y) * x2); \
        atomicAdd(&acc[((w3.x >> COLBITS) & (SUB_ROWS - 1)) * LATENT + lane], __int_as_float(w3.y) * x3); \
        atomicAdd(&acc[((w4.x >> COLBITS) & (SUB_ROWS - 1)) * LATENT + lane], __int_as_float(w4.y) * x4); \
        atomicAdd(&acc[((w5.x >> COLBITS) & (SUB_ROWS - 1)) * LATENT + lane], __int_as_float(w5.y) * x5); \
        atomicAdd(&acc[((w6.x >> COLBITS) & (SUB_ROWS - 1)) * LATENT + lane], __int_as_float(w6.y) * x6); \
        atomicAdd(&acc[((w7.x >> COLBITS) & (SUB_ROWS - 1)) * LATENT + lane], __int_as_float(w7.y) * x7); \
    }                                                                                   \
    for (; i < we; ++i) {                                                               \
        int2 w = tmp[i];                                                                \
        float xv = bf2f(SRC[(size_t)(w.x & COL_MASK) * LATENT + lane]);                 \
        atomicAdd(&acc[((w.x >> COLBITS) & (SUB_ROWS - 1)) * LATENT + lane], __int_as_float(w.y) * xv); \
    }                                                                                   \
    __syncthreads();

// Hop 1: acc -> ax1 (bf16)
__global__ void __launch_bounds__(256) bucket_gather1_kernel(
        const int2* __restrict__ tmp, const int* __restrict__ tstart,
        const int* __restrict__ stot, const unsigned short* __restrict__ xb,
        unsigned short* __restrict__ axb, int N) {
    HOP_BODY(xb)
    int base = s << SUB_SHIFT;
    int nr = N - base; if (nr > SUB_ROWS) nr = SUB_ROWS;
    for (int r = wid; r < nr; r += 4)
        axb[(size_t)(base + r) * LATENT + lane] = f2bf(acc[r * LATENT + lane]);
}

// Hop 2 fused epilogue: out = sigmoid(alpha[row]) * acc - x[row]   (f32)
__global__ void __launch_bounds__(256) bucket_gather2_kernel(
        const int2* __restrict__ tmp, const int* __restrict__ tstart,
        const int* __restrict__ stot, const unsigned short* __restrict__ axb,
        const float* __restrict__ alpha, const float* __restrict__ x,
        float* __restrict__ out, int N) {
    HOP_BODY(axb)
    int base = s << SUB_SHIFT;
    int nr = N - base; if (nr > SUB_ROWS) nr = SUB_ROWS;
    for (int r = wid; r < nr; r += 4) {
        int row = base + r;
        float a = 1.0f / (1.0f + __expf(-alpha[row]));
        out[(size_t)row * LATENT + lane] =
            a * acc[r * LATENT + lane] - x[(size_t)row * LATENT + lane];
    }
}

// ---------------------------------------------------------------------------
// Fallback: atomic scatter path (if workspace too small)
// ---------------------------------------------------------------------------
__global__ void spmm_atomic_kernel(const int* __restrict__ rows, const int* __restrict__ cols,
                                   const float* __restrict__ vals, const float* __restrict__ x,
                                   float* __restrict__ y, int E) {
    long long tid = (long long)blockIdx.x * blockDim.x + threadIdx.x;
    long long total = (long long)E * 16;
    long long stride = (long long)gridDim.x * blockDim.x;
    for (; tid < total; tid += stride) {
        int e = (int)(tid >> 4);
        int q = (int)(tid & 15);
        int r = rows[e];
        int c = cols[e];
        float v = vals[e];
        float4 xv = reinterpret_cast<const float4*>(x)[(size_t)c * 16 + q];
        float* yp = y + (size_t)r * LATENT + q * 4;
        atomicAdd(yp + 0, v * xv.x);
        atomicAdd(yp + 1, v * xv.y);
        atomicAdd(yp + 2, v * xv.z);
        atomicAdd(yp + 3, v * xv.w);
    }
}

__global__ void finalize_kernel(const float* __restrict__ alpha, const float* __restrict__ x,
                                float* __restrict__ out, int N) {
    long long tid = (long long)blockIdx.x * blockDim.x + threadIdx.x;
    long long total = (long long)N * 16;
    long long stride = (long long)gridDim.x * blockDim.x;
    for (; tid < total; tid += stride) {
        int i = (int)(tid >> 4);
        float a = 1.0f / (1.0f + __expf(-alpha[i]));
        float4 o = reinterpret_cast<float4*>(out)[tid];
        float4 xv = reinterpret_cast<const float4*>(x)[tid];
        o.x = a * o.x - xv.x;
        o.y = a * o.y - xv.y;
        o.z = a * o.z - xv.z;
        o.w = a * o.w - xv.w;
        reinterpret_cast<float4*>(out)[tid] = o;
    }
}

// ---------------------------------------------------------------------------

extern "C" void kernel_launch(void* const* d_in, const int* in_sizes, int n_in,
                              void* d_out, int out_size, void* d_ws, size_t ws_size,
                              hipStream_t stream) {
    // setup_inputs order: t, x, alpha_train, edge_rows, edge_cols, edge_vals
    const float* x     = (const float*)d_in[1];
    const float* alpha = (const float*)d_in[2];
    const int*   rows  = (const int*)d_in[3];
    const int*   cols  = (const int*)d_in[4];
    const float* vals  = (const float*)d_in[5];

    const int N = in_sizes[2];   // 100000
    const int E = in_sizes[3];   // 3200000
    float* out = (float*)d_out;

    const int nsub   = (N + SUB_ROWS - 1) >> SUB_SHIFT;   // 782
    const int ntiles = (E + TILE - 1) / TILE;             // 391

    auto align256 = [](size_t v) { return (v + 255) & ~(size_t)255; };

    size_t o_tmp    = 0;
    size_t tmp_n    = (size_t)E + 8 * (size_t)nsub;
    size_t o_xbf    = align256(o_tmp + tmp_n * sizeof(int2));
    size_t o_axbf   = align256(o_xbf + (size_t)N * LATENT * sizeof(unsigned short));
    size_t o_part   = align256(o_axbf + (size_t)N * LATENT * sizeof(unsigned short));
    size_t o_tot    = align256(o_part + (size_t)HIST_BLOCKS * nsub * sizeof(int));
    size_t o_tstart = align256(o_tot + (size_t)nsub * sizeof(int));
    size_t o_stot   = align256(o_tstart + (size_t)nsub * sizeof(int));
    size_t o_gcur   = align256(o_stot + (size_t)nsub * sizeof(int));
    size_t needed   = o_gcur + (size_t)nsub * sizeof(int);

    if (ws_size >= needed && nsub <= NSUB_PAD && N <= (1 << COLBITS)) {
        char* ws = (char*)d_ws;
        int2*           tmp    = (int2*)(ws + o_tmp);
        unsigned short* xbf    = (unsigned short*)(ws + o_xbf);
        unsigned short* axbf   = (unsigned short*)(ws + o_axbf);
        int*            part   = (int*)(ws + o_part);
        int*            tot    = (int*)(ws + o_tot);
        int*            tstart = (int*)(ws + o_tstart);
        int*            stot   = (int*)(ws + o_stot);
        int*            gcur   = (int*)(ws + o_gcur);

        // CSR-bucket metadata + bf16 operand table (independent kernels)
        subhist_kernel<<<HIST_BLOCKS, 256, 0, stream>>>(rows, part, E, nsub);
        reduce_partials_kernel<<<nsub, 256, 0, stream>>>(part, tot, nsub, HIST_BLOCKS);
        subscan_kernel<<<1, 256, 0, stream>>>(tot, tstart, stot, gcur, nsub);
        long long n4 = (long long)N * (LATENT / 4);
        conv_bf16_kernel<<<2048, 256, 0, stream>>>(x, xbf, n4);

        // Bin edges by 128-row bucket (write-amp-free)
        binscatter_kernel<<<ntiles, 256, 0, stream>>>(rows, cols, vals, gcur, tmp, E, nsub);

        // Two fused gather+accumulate hops
        bucket_gather1_kernel<<<nsub, 256, 0, stream>>>(tmp, tstart, stot, xbf, axbf, N);
        bucket_gather2_kernel<<<nsub, 256, 0, stream>>>(tmp, tstart, stot, axbf,
                                                        alpha, x, out, N);
        return;
    }

    // Fallback: atomic scatter path
    {
        float* ax1 = (float*)d_ws;
        const size_t feat_bytes = (size_t)N * LATENT * sizeof(float);
        hipMemsetAsync(ax1, 0, feat_bytes, stream);
        hipMemsetAsync(out, 0, feat_bytes, stream);
        const int block = 256;
        long long work = (long long)E * 16;
        int grid_spmm = (int)((work + block - 1) / block);
        spmm_atomic_kernel<<<grid_spmm, block, 0, stream>>>(rows, cols, vals, x, ax1, E);
        spmm_atomic_kernel<<<grid_spmm, block, 0, stream>>>(rows, cols, vals, ax1, out, E);
        long long fwork = (long long)N * 16;
        int grid_fin = (int)((fwork + block - 1) / block);
        finalize_kernel<<<grid_fin, block, 0, stream>>>(alpha, x, out, N);
    }
}

// Round 8
// 310.261 us; speedup vs baseline: 8.9645x; 8.9645x over previous
//
#include <hip/hip_runtime.h>

#define LATENT 64
#define SUB_SHIFT 7
#define SUB_ROWS 128
#define COLBITS 17
#define COL_MASK ((1 << COLBITS) - 1)
#define HIST_BLOCKS 256
#define TILE 8192
#define NSUB_PAD 1024

__device__ __forceinline__ unsigned short f2bf(float f) {
    unsigned u = __float_as_uint(f);
    unsigned r = (u + 0x7FFFu + ((u >> 16) & 1u)) >> 16;   // round-nearest-even
    return (unsigned short)r;
}
__device__ __forceinline__ float bf2f(unsigned short h) {
    return __uint_as_float(((unsigned)h) << 16);
}

// ---------------------------------------------------------------------------
// Kernel A: per-block sub-bucket histogram partials (no global atomics)
// ---------------------------------------------------------------------------
__global__ void subhist_kernel(const int* __restrict__ rows, int* __restrict__ part,
                               int E, int nsub) {
    __shared__ int h[NSUB_PAD];
    int t = threadIdx.x;
    for (int i = t; i < NSUB_PAD; i += blockDim.x) h[i] = 0;
    __syncthreads();
    for (int e = blockIdx.x * blockDim.x + t; e < E; e += gridDim.x * blockDim.x)
        atomicAdd(&h[rows[e] >> SUB_SHIFT], 1);
    __syncthreads();
    for (int i = t; i < nsub; i += blockDim.x) part[blockIdx.x * nsub + i] = h[i];
}

// ---------------------------------------------------------------------------
// Kernel A2: parallel reduction of partials -> tot[s]. One block per sub-bucket.
// ---------------------------------------------------------------------------
__global__ void reduce_partials_kernel(const int* __restrict__ part, int* __restrict__ tot,
                                       int nsub, int nblk) {
    __shared__ int s[256];
    int sidx = blockIdx.x;
    int t = threadIdx.x;
    int acc = 0;
    for (int b = t; b < nblk; b += 256) acc += part[b * nsub + sidx];
    s[t] = acc;
    __syncthreads();
    for (int o = 128; o > 0; o >>= 1) {
        if (t < o) s[t] += s[t + o];
        __syncthreads();
    }
    if (t == 0) tot[sidx] = s[0];
}

// ---------------------------------------------------------------------------
// Kernel B (1 block): exclusive scan of tot -> csr0, tstart, stot, gcur
// tstart[s] = csr0[s] + 8*s  (8-payload gap => bins never share a line)
// ---------------------------------------------------------------------------
__global__ void subscan_kernel(const int* __restrict__ tot_in, int* __restrict__ csr0,
                               int* __restrict__ tstart, int* __restrict__ stot,
                               int* __restrict__ gcur, int nsub) {
    __shared__ int tot[NSUB_PAD];
    __shared__ int sc[256];
    int t = threadIdx.x;
    for (int i = t; i < NSUB_PAD; i += 256) tot[i] = (i < nsub) ? tot_in[i] : 0;
    __syncthreads();
    int c0 = tot[4 * t], c1 = tot[4 * t + 1], c2 = tot[4 * t + 2], c3 = tot[4 * t + 3];
    int csum = c0 + c1 + c2 + c3;
    sc[t] = csum;
    __syncthreads();
    for (int o = 1; o < 256; o <<= 1) {
        int u = (t >= o) ? sc[t - o] : 0;
        __syncthreads();
        sc[t] += u;
        __syncthreads();
    }
    int pre = sc[t] - csum;   // exclusive chunk base
    int s0 = 4 * t;
    if (s0 < nsub)     { csr0[s0] = pre;     stot[s0] = c0;     int ts = pre + 8 * s0;       tstart[s0] = ts;     gcur[s0] = ts; }
    pre += c0;
    if (s0 + 1 < nsub) { csr0[s0 + 1] = pre; stot[s0 + 1] = c1; int ts = pre + 8 * (s0 + 1); tstart[s0 + 1] = ts; gcur[s0 + 1] = ts; }
    pre += c1;
    if (s0 + 2 < nsub) { csr0[s0 + 2] = pre; stot[s0 + 2] = c2; int ts = pre + 8 * (s0 + 2); tstart[s0 + 2] = ts; gcur[s0 + 2] = ts; }
    pre += c2;
    if (s0 + 3 < nsub) { csr0[s0 + 3] = pre; stot[s0 + 3] = c3; int ts = pre + 8 * (s0 + 3); tstart[s0 + 3] = ts; gcur[s0 + 3] = ts; }
}

// ---------------------------------------------------------------------------
// f32 -> bf16 table, vectorized 4 at a time
// ---------------------------------------------------------------------------
__global__ void conv_bf16_kernel(const float* __restrict__ in,
                                 unsigned short* __restrict__ outb, long long n4) {
    long long i = (long long)blockIdx.x * blockDim.x + threadIdx.x;
    long long stride = (long long)gridDim.x * blockDim.x;
    for (; i < n4; i += stride) {
        float4 f = reinterpret_cast<const float4*>(in)[i];
        ushort4 o;
        o.x = f2bf(f.x); o.y = f2bf(f.y); o.z = f2bf(f.z); o.w = f2bf(f.w);
        reinterpret_cast<ushort4*>(outb)[i] = o;
    }
}

// ---------------------------------------------------------------------------
// Pass 1: tile-local LDS bucket sort, then append contiguous runs to bins.
// ---------------------------------------------------------------------------
__global__ void __launch_bounds__(256, 2) binscatter_kernel(
        const int* __restrict__ rows, const int* __restrict__ cols,
        const float* __restrict__ vals, int* __restrict__ gcur,
        int2* __restrict__ tmp, int E, int nsub) {
    __shared__ int hist[NSUB_PAD];
    __shared__ int base[NSUB_PAD];
    __shared__ int gbase[NSUB_PAD];
    __shared__ int2 stage[TILE];
    __shared__ int sc[256];
    int t = threadIdx.x;
    int tb = blockIdx.x * TILE;
    int tilecnt = E - tb; if (tilecnt > TILE) tilecnt = TILE;

    for (int i = t; i < NSUB_PAD; i += 256) hist[i] = 0;
    __syncthreads();
    #pragma unroll
    for (int k = 0; k < TILE / 256; ++k) {
        int e = tb + k * 256 + t;
        if (e < E) atomicAdd(&hist[rows[e] >> SUB_SHIFT], 1);
    }
    __syncthreads();
    int c0 = hist[4 * t], c1 = hist[4 * t + 1], c2 = hist[4 * t + 2], c3 = hist[4 * t + 3];
    int csum = c0 + c1 + c2 + c3;
    sc[t] = csum;
    __syncthreads();
    for (int o = 1; o < 256; o <<= 1) {
        int u = (t >= o) ? sc[t - o] : 0;
        __syncthreads();
        sc[t] += u;
        __syncthreads();
    }
    int ex = sc[t] - csum;
    base[4 * t] = ex;
    base[4 * t + 1] = ex + c0;
    base[4 * t + 2] = ex + c0 + c1;
    base[4 * t + 3] = ex + c0 + c1 + c2;
    __syncthreads();
    for (int i = t; i < NSUB_PAD; i += 256) hist[i] = 0;
    __syncthreads();
    #pragma unroll
    for (int k = 0; k < TILE / 256; ++k) {
        int e = tb + k * 256 + t;
        if (e < E) {
            int r = rows[e];
            int b = r >> SUB_SHIFT;
            int pos = base[b] + atomicAdd(&hist[b], 1);
            stage[pos] = make_int2(cols[e] | ((r & (SUB_ROWS - 1)) << COLBITS),
                                   __float_as_int(vals[e]));
        }
    }
    __syncthreads();
    for (int i = t; i < nsub; i += 256) {
        int n = hist[i];
        int gb = 0;
        if (n > 0) gb = atomicAdd(&gcur[i], n);
        gbase[i] = gb - base[i];
    }
    __syncthreads();
    for (int p = t; p < tilecnt; p += 256) {
        int lo = 0, hi = nsub;
        while (hi - lo > 1) { int mid = (lo + hi) >> 1; if (base[mid] <= p) lo = mid; else hi = mid; }
        tmp[gbase[lo] + p] = stage[p];
    }
}

// ---------------------------------------------------------------------------
// Pass 2: one block per sub-bucket -> per-row counts, off/cnt, sorted spair.
// ---------------------------------------------------------------------------
__global__ void subsort_kernel(const int2* __restrict__ tmp, const int* __restrict__ tstart,
                               const int* __restrict__ stot, const int* __restrict__ csr0,
                               int* __restrict__ off, int* __restrict__ cnt,
                               int2* __restrict__ spair, int N) {
    __shared__ int lcnt[SUB_ROWS], lpos[SUB_ROWS], lcur[SUB_ROWS];
    int s = blockIdx.x;
    int t = threadIdx.x;
    int beg = tstart[s], n = stot[s], c0 = csr0[s];
    if (t < SUB_ROWS) lcnt[t] = 0;
    __syncthreads();
    for (int i = t; i < n; i += blockDim.x)
        atomicAdd(&lcnt[(tmp[beg + i].x >> COLBITS) & (SUB_ROWS - 1)], 1);
    __syncthreads();
    if (t < SUB_ROWS) lpos[t] = lcnt[t];
    __syncthreads();
    for (int o = 1; o < SUB_ROWS; o <<= 1) {
        int u = (t < SUB_ROWS && t >= o) ? lpos[t - o] : 0;
        __syncthreads();
        if (t < SUB_ROWS) lpos[t] += u;
        __syncthreads();
    }
    if (t < SUB_ROWS) {
        int excl = lpos[t] - lcnt[t];
        lcur[t] = excl;
        int row = (s << SUB_SHIFT) + t;
        if (row < N) { off[row] = c0 + excl; cnt[row] = lcnt[t]; }
    }
    __syncthreads();
    for (int i = t; i < n; i += blockDim.x) {
        int2 w = tmp[beg + i];
        int rl = (w.x >> COLBITS) & (SUB_ROWS - 1);
        int p = atomicAdd(&lcur[rl], 1);
        spair[c0 + p] = make_int2(w.x & COL_MASK, w.y);
    }
}

// ---------------------------------------------------------------------------
// Gather SpMM hops: one 64-lane wave per output row; lane = feature index.
// Operand tables are bf16 (halved gather bytes, L2-resident); f32 accumulate.
// ---------------------------------------------------------------------------
__global__ void spmm_gather1_kernel(const int* __restrict__ off, const int* __restrict__ cnt,
                                    const int2* __restrict__ spair,
                                    const unsigned short* __restrict__ xb,
                                    unsigned short* __restrict__ axb, int N) {
    int wid = blockIdx.x * (blockDim.x >> 6) + (threadIdx.x >> 6);
    int lane = threadIdx.x & 63;
    if (wid >= N) return;
    int e = off[wid];
    int end = e + cnt[wid];
    float acc = 0.f;
    for (; e + 8 <= end; e += 8) {
        int2 p0 = spair[e], p1 = spair[e + 1], p2 = spair[e + 2], p3 = spair[e + 3];
        int2 p4 = spair[e + 4], p5 = spair[e + 5], p6 = spair[e + 6], p7 = spair[e + 7];
        acc += __int_as_float(p0.y) * bf2f(xb[(size_t)p0.x * LATENT + lane]);
        acc += __int_as_float(p1.y) * bf2f(xb[(size_t)p1.x * LATENT + lane]);
        acc += __int_as_float(p2.y) * bf2f(xb[(size_t)p2.x * LATENT + lane]);
        acc += __int_as_float(p3.y) * bf2f(xb[(size_t)p3.x * LATENT + lane]);
        acc += __int_as_float(p4.y) * bf2f(xb[(size_t)p4.x * LATENT + lane]);
        acc += __int_as_float(p5.y) * bf2f(xb[(size_t)p5.x * LATENT + lane]);
        acc += __int_as_float(p6.y) * bf2f(xb[(size_t)p6.x * LATENT + lane]);
        acc += __int_as_float(p7.y) * bf2f(xb[(size_t)p7.x * LATENT + lane]);
    }
    for (; e < end; ++e) {
        int2 p = spair[e];
        acc += __int_as_float(p.y) * bf2f(xb[(size_t)p.x * LATENT + lane]);
    }
    axb[(size_t)wid * LATENT + lane] = f2bf(acc);
}

__global__ void spmm_gather2_kernel(const int* __restrict__ off, const int* __restrict__ cnt,
                                    const int2* __restrict__ spair,
                                    const unsigned short* __restrict__ axb,
                                    const float* __restrict__ alpha,
                                    const float* __restrict__ x,
                                    float* __restrict__ out, int N) {
    int wid = blockIdx.x * (blockDim.x >> 6) + (threadIdx.x >> 6);
    int lane = threadIdx.x & 63;
    if (wid >= N) return;
    int e = off[wid];
    int end = e + cnt[wid];
    float acc = 0.f;
    for (; e + 8 <= end; e += 8) {
        int2 p0 = spair[e], p1 = spair[e + 1], p2 = spair[e + 2], p3 = spair[e + 3];
        int2 p4 = spair[e + 4], p5 = spair[e + 5], p6 = spair[e + 6], p7 = spair[e + 7];
        acc += __int_as_float(p0.y) * bf2f(axb[(size_t)p0.x * LATENT + lane]);
        acc += __int_as_float(p1.y) * bf2f(axb[(size_t)p1.x * LATENT + lane]);
        acc += __int_as_float(p2.y) * bf2f(axb[(size_t)p2.x * LATENT + lane]);
        acc += __int_as_float(p3.y) * bf2f(axb[(size_t)p3.x * LATENT + lane]);
        acc += __int_as_float(p4.y) * bf2f(axb[(size_t)p4.x * LATENT + lane]);
        acc += __int_as_float(p5.y) * bf2f(axb[(size_t)p5.x * LATENT + lane]);
        acc += __int_as_float(p6.y) * bf2f(axb[(size_t)p6.x * LATENT + lane]);
        acc += __int_as_float(p7.y) * bf2f(axb[(size_t)p7.x * LATENT + lane]);
    }
    for (; e < end; ++e) {
        int2 p = spair[e];
        acc += __int_as_float(p.y) * bf2f(axb[(size_t)p.x * LATENT + lane]);
    }
    float a = 1.0f / (1.0f + __expf(-alpha[wid]));
    out[(size_t)wid * LATENT + lane] = a * acc - x[(size_t)wid * LATENT + lane];
}

// ---------------------------------------------------------------------------
// Fallback: atomic scatter path (if workspace too small)
// ---------------------------------------------------------------------------
__global__ void spmm_atomic_kernel(const int* __restrict__ rows, const int* __restrict__ cols,
                                   const float* __restrict__ vals, const float* __restrict__ x,
                                   float* __restrict__ y, int E) {
    long long tid = (long long)blockIdx.x * blockDim.x + threadIdx.x;
    long long total = (long long)E * 16;
    long long stride = (long long)gridDim.x * blockDim.x;
    for (; tid < total; tid += stride) {
        int e = (int)(tid >> 4);
        int q = (int)(tid & 15);
        int r = rows[e];
        int c = cols[e];
        float v = vals[e];
        float4 xv = reinterpret_cast<const float4*>(x)[(size_t)c * 16 + q];
        float* yp = y + (size_t)r * LATENT + q * 4;
        atomicAdd(yp + 0, v * xv.x);
        atomicAdd(yp + 1, v * xv.y);
        atomicAdd(yp + 2, v * xv.z);
        atomicAdd(yp + 3, v * xv.w);
    }
}

__global__ void finalize_kernel(const float* __restrict__ alpha, const float* __restrict__ x,
                                float* __restrict__ out, int N) {
    long long tid = (long long)blockIdx.x * blockDim.x + threadIdx.x;
    long long total = (long long)N * 16;
    long long stride = (long long)gridDim.x * blockDim.x;
    for (; tid < total; tid += stride) {
        int i = (int)(tid >> 4);
        float a = 1.0f / (1.0f + __expf(-alpha[i]));
        float4 o = reinterpret_cast<float4*>(out)[tid];
        float4 xv = reinterpret_cast<const float4*>(x)[tid];
        o.x = a * o.x - xv.x;
        o.y = a * o.y - xv.y;
        o.z = a * o.z - xv.z;
        o.w = a * o.w - xv.w;
        reinterpret_cast<float4*>(out)[tid] = o;
    }
}

// ---------------------------------------------------------------------------

extern "C" void kernel_launch(void* const* d_in, const int* in_sizes, int n_in,
                              void* d_out, int out_size, void* d_ws, size_t ws_size,
                              hipStream_t stream) {
    // setup_inputs order: t, x, alpha_train, edge_rows, edge_cols, edge_vals
    const float* x     = (const float*)d_in[1];
    const float* alpha = (const float*)d_in[2];
    const int*   rows  = (const int*)d_in[3];
    const int*   cols  = (const int*)d_in[4];
    const float* vals  = (const float*)d_in[5];

    const int N = in_sizes[2];   // 100000
    const int E = in_sizes[3];   // 3200000
    float* out = (float*)d_out;

    const int block = 256;
    const int nsub   = (N + SUB_ROWS - 1) >> SUB_SHIFT;   // 782
    const int ntiles = (E + TILE - 1) / TILE;             // 391

    auto align256 = [](size_t v) { return (v + 255) & ~(size_t)255; };

    // Region A holds: tmp (bin-sorted edges, alive through subsort), THEN
    // after subsort it is reused for xbf (bf16 x) + axbf (bf16 ax1).
    size_t tmp_bytes  = ((size_t)E + 8 * (size_t)nsub) * sizeof(int2);
    size_t xbf_bytes  = (size_t)N * LATENT * sizeof(unsigned short);
    size_t o_axbf_inA = align256(xbf_bytes);
    size_t bf_bytes   = o_axbf_inA + xbf_bytes;
    size_t RA = tmp_bytes > bf_bytes ? tmp_bytes : bf_bytes;

    size_t o_tmp    = 0;
    size_t o_spair  = align256(o_tmp + RA);
    size_t o_off    = align256(o_spair + (size_t)E * sizeof(int2));
    size_t o_cnt    = align256(o_off + (size_t)N * sizeof(int));
    size_t o_csr0   = align256(o_cnt + (size_t)N * sizeof(int));
    size_t o_tstart = align256(o_csr0 + (size_t)nsub * sizeof(int));
    size_t o_stot   = align256(o_tstart + (size_t)nsub * sizeof(int));
    size_t o_gcur   = align256(o_stot + (size_t)nsub * sizeof(int));
    size_t o_tot    = align256(o_gcur + (size_t)nsub * sizeof(int));
    size_t needed   = o_tot + (size_t)nsub * sizeof(int);
    size_t part_bytes = (size_t)HIST_BLOCKS * nsub * sizeof(int);

    if (ws_size >= needed && nsub <= NSUB_PAD && N <= (1 << COLBITS) &&
        part_bytes <= (size_t)E * sizeof(int2)) {
        char* ws = (char*)d_ws;
        int2*           tmp    = (int2*)(ws + o_tmp);
        unsigned short* xbf    = (unsigned short*)(ws + o_tmp);          // after subsort
        unsigned short* axbf   = (unsigned short*)(ws + o_tmp + o_axbf_inA);
        int2*           spair  = (int2*)(ws + o_spair);
        int*            part   = (int*)(ws + o_spair);   // aliases spair (earlier lifetime)
        int*            off    = (int*)(ws + o_off);
        int*            cnt    = (int*)(ws + o_cnt);
        int*            csr0   = (int*)(ws + o_csr0);
        int*            tstart = (int*)(ws + o_tstart);
        int*            stot   = (int*)(ws + o_stot);
        int*            gcur   = (int*)(ws + o_gcur);
        int*            tot    = (int*)(ws + o_tot);

        // CSR-bucket metadata
        subhist_kernel<<<HIST_BLOCKS, 256, 0, stream>>>(rows, part, E, nsub);
        reduce_partials_kernel<<<nsub, 256, 0, stream>>>(part, tot, nsub, HIST_BLOCKS);
        subscan_kernel<<<1, 256, 0, stream>>>(tot, csr0, tstart, stot, gcur, nsub);

        // Bin + sort edges into CSR order
        binscatter_kernel<<<ntiles, 256, 0, stream>>>(rows, cols, vals, gcur, tmp, E, nsub);
        subsort_kernel<<<nsub, 256, 0, stream>>>(tmp, tstart, stot, csr0, off, cnt, spair, N);

        // tmp dead -> build bf16 x table in its region
        long long n4 = (long long)N * (LATENT / 4);
        conv_bf16_kernel<<<2048, 256, 0, stream>>>(x, xbf, n4);

        // Two gather hops (wave per row), bf16 operand tables
        int rows_per_block = block / 64;
        int grid_rows = (N + rows_per_block - 1) / rows_per_block;
        spmm_gather1_kernel<<<grid_rows, block, 0, stream>>>(off, cnt, spair, xbf, axbf, N);
        spmm_gather2_kernel<<<grid_rows, block, 0, stream>>>(off, cnt, spair, axbf,
                                                             alpha, x, out, N);
        return;
    }

    // Fallback: atomic scatter path
    {
        float* ax1 = (float*)d_ws;
        const size_t feat_bytes = (size_t)N * LATENT * sizeof(float);
        hipMemsetAsync(ax1, 0, feat_bytes, stream);
        hipMemsetAsync(out, 0, feat_bytes, stream);
        long long work = (long long)E * 16;
        int grid_spmm = (int)((work + block - 1) / block);
        spmm_atomic_kernel<<<grid_spmm, block, 0, stream>>>(rows, cols, vals, x, ax1, E);
        spmm_atomic_kernel<<<grid_spmm, block, 0, stream>>>(rows, cols, vals, ax1, out, E);
        long long fwork = (long long)N * 16;
        int grid_fin = (int)((fwork + block - 1) / block);
        finalize_kernel<<<grid_fin, block, 0, stream>>>(alpha, x, out, N);
    }
}

// Round 9
// 285.291 us; speedup vs baseline: 9.7491x; 1.0875x over previous
//
#include <hip/hip_runtime.h>

#define LATENT 64
#define SUB_SHIFT 7
#define SUB_ROWS 128
#define COLBITS 17
#define COL_MASK ((1 << COLBITS) - 1)
#define HIST_BLOCKS 256
#define TILE 8192
#define NSUB_PAD 1024

__device__ __forceinline__ unsigned short f2bf(float f) {
    unsigned u = __float_as_uint(f);
    unsigned r = (u + 0x7FFFu + ((u >> 16) & 1u)) >> 16;   // round-nearest-even
    return (unsigned short)r;
}
__device__ __forceinline__ float bf2f(unsigned short h) {
    return __uint_as_float(((unsigned)h) << 16);
}

// ---------------------------------------------------------------------------
// Kernel A: per-block sub-bucket histogram partials (no global atomics)
// ---------------------------------------------------------------------------
__global__ void subhist_kernel(const int* __restrict__ rows, int* __restrict__ part,
                               int E, int nsub) {
    __shared__ int h[NSUB_PAD];
    int t = threadIdx.x;
    for (int i = t; i < NSUB_PAD; i += blockDim.x) h[i] = 0;
    __syncthreads();
    for (int e = blockIdx.x * blockDim.x + t; e < E; e += gridDim.x * blockDim.x)
        atomicAdd(&h[rows[e] >> SUB_SHIFT], 1);
    __syncthreads();
    for (int i = t; i < nsub; i += blockDim.x) part[blockIdx.x * nsub + i] = h[i];
}

// ---------------------------------------------------------------------------
// Kernel A2: parallel reduction of partials -> tot[s]. One block per sub-bucket.
// ---------------------------------------------------------------------------
__global__ void reduce_partials_kernel(const int* __restrict__ part, int* __restrict__ tot,
                                       int nsub, int nblk) {
    __shared__ int s[256];
    int sidx = blockIdx.x;
    int t = threadIdx.x;
    int acc = 0;
    for (int b = t; b < nblk; b += 256) acc += part[b * nsub + sidx];
    s[t] = acc;
    __syncthreads();
    for (int o = 128; o > 0; o >>= 1) {
        if (t < o) s[t] += s[t + o];
        __syncthreads();
    }
    if (t == 0) tot[sidx] = s[0];
}

// ---------------------------------------------------------------------------
// Kernel B (1 block): exclusive scan of tot -> csr0, tstart, stot, gcur
// ---------------------------------------------------------------------------
__global__ void subscan_kernel(const int* __restrict__ tot_in, int* __restrict__ csr0,
                               int* __restrict__ tstart, int* __restrict__ stot,
                               int* __restrict__ gcur, int nsub) {
    __shared__ int tot[NSUB_PAD];
    __shared__ int sc[256];
    int t = threadIdx.x;
    for (int i = t; i < NSUB_PAD; i += 256) tot[i] = (i < nsub) ? tot_in[i] : 0;
    __syncthreads();
    int c0 = tot[4 * t], c1 = tot[4 * t + 1], c2 = tot[4 * t + 2], c3 = tot[4 * t + 3];
    int csum = c0 + c1 + c2 + c3;
    sc[t] = csum;
    __syncthreads();
    for (int o = 1; o < 256; o <<= 1) {
        int u = (t >= o) ? sc[t - o] : 0;
        __syncthreads();
        sc[t] += u;
        __syncthreads();
    }
    int pre = sc[t] - csum;   // exclusive chunk base
    int s0 = 4 * t;
    if (s0 < nsub)     { csr0[s0] = pre;     stot[s0] = c0;     int ts = pre + 8 * s0;       tstart[s0] = ts;     gcur[s0] = ts; }
    pre += c0;
    if (s0 + 1 < nsub) { csr0[s0 + 1] = pre; stot[s0 + 1] = c1; int ts = pre + 8 * (s0 + 1); tstart[s0 + 1] = ts; gcur[s0 + 1] = ts; }
    pre += c1;
    if (s0 + 2 < nsub) { csr0[s0 + 2] = pre; stot[s0 + 2] = c2; int ts = pre + 8 * (s0 + 2); tstart[s0 + 2] = ts; gcur[s0 + 2] = ts; }
    pre += c2;
    if (s0 + 3 < nsub) { csr0[s0 + 3] = pre; stot[s0 + 3] = c3; int ts = pre + 8 * (s0 + 3); tstart[s0 + 3] = ts; gcur[s0 + 3] = ts; }
}

// ---------------------------------------------------------------------------
// f32 -> bf16 table, vectorized 4 at a time
// ---------------------------------------------------------------------------
__global__ void conv_bf16_kernel(const float* __restrict__ in,
                                 unsigned short* __restrict__ outb, long long n4) {
    long long i = (long long)blockIdx.x * blockDim.x + threadIdx.x;
    long long stride = (long long)gridDim.x * blockDim.x;
    for (; i < n4; i += stride) {
        float4 f = reinterpret_cast<const float4*>(in)[i];
        ushort4 o;
        o.x = f2bf(f.x); o.y = f2bf(f.y); o.z = f2bf(f.z); o.w = f2bf(f.w);
        reinterpret_cast<ushort4*>(outb)[i] = o;
    }
}

// ---------------------------------------------------------------------------
// Pass 1: tile-local LDS bucket sort, then append contiguous runs to bins.
// ---------------------------------------------------------------------------
__global__ void __launch_bounds__(256, 2) binscatter_kernel(
        const int* __restrict__ rows, const int* __restrict__ cols,
        const float* __restrict__ vals, int* __restrict__ gcur,
        int2* __restrict__ tmp, int E, int nsub) {
    __shared__ int hist[NSUB_PAD];
    __shared__ int base[NSUB_PAD];
    __shared__ int gbase[NSUB_PAD];
    __shared__ int2 stage[TILE];
    __shared__ int sc[256];
    int t = threadIdx.x;
    int tb = blockIdx.x * TILE;
    int tilecnt = E - tb; if (tilecnt > TILE) tilecnt = TILE;

    for (int i = t; i < NSUB_PAD; i += 256) hist[i] = 0;
    __syncthreads();
    #pragma unroll
    for (int k = 0; k < TILE / 256; ++k) {
        int e = tb + k * 256 + t;
        if (e < E) atomicAdd(&hist[rows[e] >> SUB_SHIFT], 1);
    }
    __syncthreads();
    int c0 = hist[4 * t], c1 = hist[4 * t + 1], c2 = hist[4 * t + 2], c3 = hist[4 * t + 3];
    int csum = c0 + c1 + c2 + c3;
    sc[t] = csum;
    __syncthreads();
    for (int o = 1; o < 256; o <<= 1) {
        int u = (t >= o) ? sc[t - o] : 0;
        __syncthreads();
        sc[t] += u;
        __syncthreads();
    }
    int ex = sc[t] - csum;
    base[4 * t] = ex;
    base[4 * t + 1] = ex + c0;
    base[4 * t + 2] = ex + c0 + c1;
    base[4 * t + 3] = ex + c0 + c1 + c2;
    __syncthreads();
    for (int i = t; i < NSUB_PAD; i += 256) hist[i] = 0;
    __syncthreads();
    #pragma unroll
    for (int k = 0; k < TILE / 256; ++k) {
        int e = tb + k * 256 + t;
        if (e < E) {
            int r = rows[e];
            int b = r >> SUB_SHIFT;
            int pos = base[b] + atomicAdd(&hist[b], 1);
            stage[pos] = make_int2(cols[e] | ((r & (SUB_ROWS - 1)) << COLBITS),
                                   __float_as_int(vals[e]));
        }
    }
    __syncthreads();
    for (int i = t; i < nsub; i += 256) {
        int n = hist[i];
        int gb = 0;
        if (n > 0) gb = atomicAdd(&gcur[i], n);
        gbase[i] = gb - base[i];
    }
    __syncthreads();
    for (int p = t; p < tilecnt; p += 256) {
        int lo = 0, hi = nsub;
        while (hi - lo > 1) { int mid = (lo + hi) >> 1; if (base[mid] <= p) lo = mid; else hi = mid; }
        tmp[gbase[lo] + p] = stage[p];
    }
}

// ---------------------------------------------------------------------------
// Pass 2: one block per sub-bucket -> offcnt (int2 per row), sorted spair.
// ---------------------------------------------------------------------------
__global__ void subsort_kernel(const int2* __restrict__ tmp, const int* __restrict__ tstart,
                               const int* __restrict__ stot, const int* __restrict__ csr0,
                               int2* __restrict__ oc, int2* __restrict__ spair, int N) {
    __shared__ int lcnt[SUB_ROWS], lpos[SUB_ROWS], lcur[SUB_ROWS];
    int s = blockIdx.x;
    int t = threadIdx.x;
    int beg = tstart[s], n = stot[s], c0 = csr0[s];
    if (t < SUB_ROWS) lcnt[t] = 0;
    __syncthreads();
    for (int i = t; i < n; i += blockDim.x)
        atomicAdd(&lcnt[(tmp[beg + i].x >> COLBITS) & (SUB_ROWS - 1)], 1);
    __syncthreads();
    if (t < SUB_ROWS) lpos[t] = lcnt[t];
    __syncthreads();
    for (int o = 1; o < SUB_ROWS; o <<= 1) {
        int u = (t < SUB_ROWS && t >= o) ? lpos[t - o] : 0;
        __syncthreads();
        if (t < SUB_ROWS) lpos[t] += u;
        __syncthreads();
    }
    if (t < SUB_ROWS) {
        int excl = lpos[t] - lcnt[t];
        lcur[t] = excl;
        int row = (s << SUB_SHIFT) + t;
        if (row < N) oc[row] = make_int2(c0 + excl, lcnt[t]);
    }
    __syncthreads();
    for (int i = t; i < n; i += blockDim.x) {
        int2 w = tmp[beg + i];
        int rl = (w.x >> COLBITS) & (SUB_ROWS - 1);
        int p = atomicAdd(&lcur[rl], 1);
        spair[c0 + p] = make_int2(w.x & COL_MASK, w.y);
    }
}

// ---------------------------------------------------------------------------
// Gather hops: one wave per row; lane l -> features {2*(l&31), 2*(l&31)+1}
// of edge-slot (l>>5). Per 2 edges: one uniform int4 spair load + one ushort2
// gather per lane. Cross-half combine via shfl_xor(32). f32 accumulate.
// ---------------------------------------------------------------------------

#define GATHER_CORE(TBL)                                                        \
    int el = lane >> 5;                                                         \
    int f  = lane & 31;                                                         \
    const unsigned* tb = (const unsigned*)(TBL);                                \
    float acc0 = 0.f, acc1 = 0.f;                                               \
    /* peel to even e so int4 loads are 16B-aligned */                          \
    if (e < end && (e & 1)) {                                                   \
        int2 w = spair[e];                                                      \
        float v = el ? 0.f : __int_as_float(w.y);                               \
        unsigned pk = tb[(size_t)w.x * 32 + f];                                 \
        acc0 += v * __uint_as_float(pk << 16);                                  \
        acc1 += v * __uint_as_float(pk & 0xFFFF0000u);                          \
        ++e;                                                                    \
    }                                                                           \
    for (; e + 8 <= end; e += 8) {                                              \
        int4 wa = *(const int4*)(spair + e);                                    \
        int4 wb = *(const int4*)(spair + e + 2);                                \
        int4 wc = *(const int4*)(spair + e + 4);                                \
        int4 wd = *(const int4*)(spair + e + 6);                                \
        int ca = el ? wa.z : wa.x;  float va = __int_as_float(el ? wa.w : wa.y);\
        int cb = el ? wb.z : wb.x;  float vb = __int_as_float(el ? wb.w : wb.y);\
        int cc = el ? wc.z : wc.x;  float vc = __int_as_float(el ? wc.w : wc.y);\
        int cd = el ? wd.z : wd.x;  float vd = __int_as_float(el ? wd.w : wd.y);\
        unsigned pa = tb[(size_t)ca * 32 + f];                                  \
        unsigned pb = tb[(size_t)cb * 32 + f];                                  \
        unsigned pc = tb[(size_t)cc * 32 + f];                                  \
        unsigned pd = tb[(size_t)cd * 32 + f];                                  \
        acc0 += va * __uint_as_float(pa << 16);                                 \
        acc1 += va * __uint_as_float(pa & 0xFFFF0000u);                         \
        acc0 += vb * __uint_as_float(pb << 16);                                 \
        acc1 += vb * __uint_as_float(pb & 0xFFFF0000u);                         \
        acc0 += vc * __uint_as_float(pc << 16);                                 \
        acc1 += vc * __uint_as_float(pc & 0xFFFF0000u);                         \
        acc0 += vd * __uint_as_float(pd << 16);                                 \
        acc1 += vd * __uint_as_float(pd & 0xFFFF0000u);                         \
    }                                                                           \
    for (; e + 2 <= end; e += 2) {                                              \
        int4 w = *(const int4*)(spair + e);                                     \
        int cx = el ? w.z : w.x;  float v = __int_as_float(el ? w.w : w.y);     \
        unsigned pk = tb[(size_t)cx * 32 + f];                                  \
        acc0 += v * __uint_as_float(pk << 16);                                  \
        acc1 += v * __uint_as_float(pk & 0xFFFF0000u);                          \
    }                                                                           \
    if (e < end) {                                                              \
        int2 w = spair[e];                                                      \
        float v = el ? 0.f : __int_as_float(w.y);                               \
        unsigned pk = tb[(size_t)w.x * 32 + f];                                 \
        acc0 += v * __uint_as_float(pk << 16);                                  \
        acc1 += v * __uint_as_float(pk & 0xFFFF0000u);                          \
    }                                                                           \
    acc0 += __shfl_xor(acc0, 32);                                               \
    acc1 += __shfl_xor(acc1, 32);

__global__ void __launch_bounds__(256) spmm_gather1_kernel(
        const int2* __restrict__ oc, const int2* __restrict__ spair,
        const unsigned short* __restrict__ xb, unsigned short* __restrict__ axb, int N) {
    int wid = blockIdx.x * (blockDim.x >> 6) + (threadIdx.x >> 6);
    int lane = threadIdx.x & 63;
    if (wid >= N) return;
    int2 o = oc[wid];
    int e = o.x, end = o.x + o.y;
    GATHER_CORE(xb)
    if (el == 0) {
        unsigned pk = (unsigned)f2bf(acc0) | ((unsigned)f2bf(acc1) << 16);
        ((unsigned*)axb)[(size_t)wid * 32 + f] = pk;
    }
}

__global__ void __launch_bounds__(256) spmm_gather2_kernel(
        const int2* __restrict__ oc, const int2* __restrict__ spair,
        const unsigned short* __restrict__ axb, const float* __restrict__ alpha,
        const float* __restrict__ x, float* __restrict__ out, int N) {
    int wid = blockIdx.x * (blockDim.x >> 6) + (threadIdx.x >> 6);
    int lane = threadIdx.x & 63;
    if (wid >= N) return;
    int2 o = oc[wid];
    int e = o.x, end = o.x + o.y;
    GATHER_CORE(axb)
    if (el == 0) {
        float a = 1.0f / (1.0f + __expf(-alpha[wid]));
        float2 xv = ((const float2*)x)[(size_t)wid * 32 + f];
        float2 ov;
        ov.x = a * acc0 - xv.x;
        ov.y = a * acc1 - xv.y;
        ((float2*)out)[(size_t)wid * 32 + f] = ov;
    }
}

// ---------------------------------------------------------------------------
// Fallback: atomic scatter path (if workspace too small)
// ---------------------------------------------------------------------------
__global__ void spmm_atomic_kernel(const int* __restrict__ rows, const int* __restrict__ cols,
                                   const float* __restrict__ vals, const float* __restrict__ x,
                                   float* __restrict__ y, int E) {
    long long tid = (long long)blockIdx.x * blockDim.x + threadIdx.x;
    long long total = (long long)E * 16;
    long long stride = (long long)gridDim.x * blockDim.x;
    for (; tid < total; tid += stride) {
        int e = (int)(tid >> 4);
        int q = (int)(tid & 15);
        int r = rows[e];
        int c = cols[e];
        float v = vals[e];
        float4 xv = reinterpret_cast<const float4*>(x)[(size_t)c * 16 + q];
        float* yp = y + (size_t)r * LATENT + q * 4;
        atomicAdd(yp + 0, v * xv.x);
        atomicAdd(yp + 1, v * xv.y);
        atomicAdd(yp + 2, v * xv.z);
        atomicAdd(yp + 3, v * xv.w);
    }
}

__global__ void finalize_kernel(const float* __restrict__ alpha, const float* __restrict__ x,
                                float* __restrict__ out, int N) {
    long long tid = (long long)blockIdx.x * blockDim.x + threadIdx.x;
    long long total = (long long)N * 16;
    long long stride = (long long)gridDim.x * blockDim.x;
    for (; tid < total; tid += stride) {
        int i = (int)(tid >> 4);
        float a = 1.0f / (1.0f + __expf(-alpha[i]));
        float4 ov = reinterpret_cast<float4*>(out)[tid];
        float4 xv = reinterpret_cast<const float4*>(x)[tid];
        ov.x = a * ov.x - xv.x;
        ov.y = a * ov.y - xv.y;
        ov.z = a * ov.z - xv.z;
        ov.w = a * ov.w - xv.w;
        reinterpret_cast<float4*>(out)[tid] = ov;
    }
}

// ---------------------------------------------------------------------------

extern "C" void kernel_launch(void* const* d_in, const int* in_sizes, int n_in,
                              void* d_out, int out_size, void* d_ws, size_t ws_size,
                              hipStream_t stream) {
    // setup_inputs order: t, x, alpha_train, edge_rows, edge_cols, edge_vals
    const float* x     = (const float*)d_in[1];
    const float* alpha = (const float*)d_in[2];
    const int*   rows  = (const int*)d_in[3];
    const int*   cols  = (const int*)d_in[4];
    const float* vals  = (const float*)d_in[5];

    const int N = in_sizes[2];   // 100000
    const int E = in_sizes[3];   // 3200000
    float* out = (float*)d_out;

    const int block = 256;
    const int nsub   = (N + SUB_ROWS - 1) >> SUB_SHIFT;   // 782
    const int ntiles = (E + TILE - 1) / TILE;             // 391

    auto align256 = [](size_t v) { return (v + 255) & ~(size_t)255; };

    // Region A: tmp (bin-sorted edges, alive through subsort), then reused
    // for xbf (bf16 x) + axbf (bf16 ax1).
    size_t tmp_bytes  = ((size_t)E + 8 * (size_t)nsub) * sizeof(int2);
    size_t xbf_bytes  = (size_t)N * LATENT * sizeof(unsigned short);
    size_t o_axbf_inA = align256(xbf_bytes);
    size_t bf_bytes   = o_axbf_inA + xbf_bytes;
    size_t RA = tmp_bytes > bf_bytes ? tmp_bytes : bf_bytes;

    size_t o_tmp    = 0;
    size_t o_spair  = align256(o_tmp + RA);
    size_t o_oc     = align256(o_spair + (size_t)E * sizeof(int2));
    size_t o_csr0   = align256(o_oc + (size_t)N * sizeof(int2));
    size_t o_tstart = align256(o_csr0 + (size_t)nsub * sizeof(int));
    size_t o_stot   = align256(o_tstart + (size_t)nsub * sizeof(int));
    size_t o_gcur   = align256(o_stot + (size_t)nsub * sizeof(int));
    size_t o_tot    = align256(o_gcur + (size_t)nsub * sizeof(int));
    size_t needed   = o_tot + (size_t)nsub * sizeof(int);
    size_t part_bytes = (size_t)HIST_BLOCKS * nsub * sizeof(int);

    if (ws_size >= needed && nsub <= NSUB_PAD && N <= (1 << COLBITS) &&
        part_bytes <= (size_t)E * sizeof(int2)) {
        char* ws = (char*)d_ws;
        int2*           tmp    = (int2*)(ws + o_tmp);
        unsigned short* xbf    = (unsigned short*)(ws + o_tmp);          // after subsort
        unsigned short* axbf   = (unsigned short*)(ws + o_tmp + o_axbf_inA);
        int2*           spair  = (int2*)(ws + o_spair);
        int*            part   = (int*)(ws + o_spair);   // aliases spair (earlier lifetime)
        int2*           oc     = (int2*)(ws + o_oc);
        int*            csr0   = (int*)(ws + o_csr0);
        int*            tstart = (int*)(ws + o_tstart);
        int*            stot   = (int*)(ws + o_stot);
        int*            gcur   = (int*)(ws + o_gcur);
        int*            tot    = (int*)(ws + o_tot);

        // CSR-bucket metadata
        subhist_kernel<<<HIST_BLOCKS, 256, 0, stream>>>(rows, part, E, nsub);
        reduce_partials_kernel<<<nsub, 256, 0, stream>>>(part, tot, nsub, HIST_BLOCKS);
        subscan_kernel<<<1, 256, 0, stream>>>(tot, csr0, tstart, stot, gcur, nsub);

        // Bin + sort edges into CSR order
        binscatter_kernel<<<ntiles, 256, 0, stream>>>(rows, cols, vals, gcur, tmp, E, nsub);
        subsort_kernel<<<nsub, 256, 0, stream>>>(tmp, tstart, stot, csr0, oc, spair, N);

        // tmp dead -> build bf16 x table in its region
        long long n4 = (long long)N * (LATENT / 4);
        conv_bf16_kernel<<<2048, 256, 0, stream>>>(x, xbf, n4);

        // Two gather hops (wave per row), packed bf16x2 lanes
        int rows_per_block = block / 64;
        int grid_rows = (N + rows_per_block - 1) / rows_per_block;
        spmm_gather1_kernel<<<grid_rows, block, 0, stream>>>(oc, spair, xbf, axbf, N);
        spmm_gather2_kernel<<<grid_rows, block, 0, stream>>>(oc, spair, axbf,
                                                             alpha, x, out, N);
        return;
    }

    // Fallback: atomic scatter path
    {
        float* ax1 = (float*)d_ws;
        const size_t feat_bytes = (size_t)N * LATENT * sizeof(float);
        hipMemsetAsync(ax1, 0, feat_bytes, stream);
        hipMemsetAsync(out, 0, feat_bytes, stream);
        long long work = (long long)E * 16;
        int grid_spmm = (int)((work + block - 1) / block);
        spmm_atomic_kernel<<<grid_spmm, block, 0, stream>>>(rows, cols, vals, x, ax1, E);
        spmm_atomic_kernel<<<grid_spmm, block, 0, stream>>>(rows, cols, vals, ax1, out, E);
        long long fwork = (long long)N * 16;
        int grid_fin = (int)((fwork + block - 1) / block);
        finalize_kernel<<<grid_fin, block, 0, stream>>>(alpha, x, out, N);
    }
}

// Round 10
// 280.407 us; speedup vs baseline: 9.9189x; 1.0174x over previous
//
#include <hip/hip_runtime.h>

#define LATENT 64
#define SUB_SHIFT 7
#define SUB_ROWS 128
#define COLBITS 17
#define COL_MASK ((1 << COLBITS) - 1)
#define HIST_BLOCKS 256
#define TILE 8192
#define NSUB_PAD 1024

__device__ __forceinline__ unsigned short f2bf(float f) {
    unsigned u = __float_as_uint(f);
    unsigned r = (u + 0x7FFFu + ((u >> 16) & 1u)) >> 16;   // round-nearest-even
    return (unsigned short)r;
}
__device__ __forceinline__ float bf2f(unsigned short h) {
    return __uint_as_float(((unsigned)h) << 16);
}

// ---------------------------------------------------------------------------
// Kernel A: per-block sub-bucket histogram partials (no global atomics)
// ---------------------------------------------------------------------------
__global__ void subhist_kernel(const int* __restrict__ rows, int* __restrict__ part,
                               int E, int nsub) {
    __shared__ int h[NSUB_PAD];
    int t = threadIdx.x;
    for (int i = t; i < NSUB_PAD; i += blockDim.x) h[i] = 0;
    __syncthreads();
    for (int e = blockIdx.x * blockDim.x + t; e < E; e += gridDim.x * blockDim.x)
        atomicAdd(&h[rows[e] >> SUB_SHIFT], 1);
    __syncthreads();
    for (int i = t; i < nsub; i += blockDim.x) part[blockIdx.x * nsub + i] = h[i];
}

// ---------------------------------------------------------------------------
// Kernel A2: parallel reduction of partials -> tot[s]. One block per sub-bucket.
// ---------------------------------------------------------------------------
__global__ void reduce_partials_kernel(const int* __restrict__ part, int* __restrict__ tot,
                                       int nsub, int nblk) {
    __shared__ int s[256];
    int sidx = blockIdx.x;
    int t = threadIdx.x;
    int acc = 0;
    for (int b = t; b < nblk; b += 256) acc += part[b * nsub + sidx];
    s[t] = acc;
    __syncthreads();
    for (int o = 128; o > 0; o >>= 1) {
        if (t < o) s[t] += s[t + o];
        __syncthreads();
    }
    if (t == 0) tot[sidx] = s[0];
}

// ---------------------------------------------------------------------------
// Kernel B (1 block): exclusive scan of tot -> csr0, tstart, stot, gcur
// ---------------------------------------------------------------------------
__global__ void subscan_kernel(const int* __restrict__ tot_in, int* __restrict__ csr0,
                               int* __restrict__ tstart, int* __restrict__ stot,
                               int* __restrict__ gcur, int nsub) {
    __shared__ int tot[NSUB_PAD];
    __shared__ int sc[256];
    int t = threadIdx.x;
    for (int i = t; i < NSUB_PAD; i += 256) tot[i] = (i < nsub) ? tot_in[i] : 0;
    __syncthreads();
    int c0 = tot[4 * t], c1 = tot[4 * t + 1], c2 = tot[4 * t + 2], c3 = tot[4 * t + 3];
    int csum = c0 + c1 + c2 + c3;
    sc[t] = csum;
    __syncthreads();
    for (int o = 1; o < 256; o <<= 1) {
        int u = (t >= o) ? sc[t - o] : 0;
        __syncthreads();
        sc[t] += u;
        __syncthreads();
    }
    int pre = sc[t] - csum;   // exclusive chunk base
    int s0 = 4 * t;
    if (s0 < nsub)     { csr0[s0] = pre;     stot[s0] = c0;     int ts = pre + 8 * s0;       tstart[s0] = ts;     gcur[s0] = ts; }
    pre += c0;
    if (s0 + 1 < nsub) { csr0[s0 + 1] = pre; stot[s0 + 1] = c1; int ts = pre + 8 * (s0 + 1); tstart[s0 + 1] = ts; gcur[s0 + 1] = ts; }
    pre += c1;
    if (s0 + 2 < nsub) { csr0[s0 + 2] = pre; stot[s0 + 2] = c2; int ts = pre + 8 * (s0 + 2); tstart[s0 + 2] = ts; gcur[s0 + 2] = ts; }
    pre += c2;
    if (s0 + 3 < nsub) { csr0[s0 + 3] = pre; stot[s0 + 3] = c3; int ts = pre + 8 * (s0 + 3); tstart[s0 + 3] = ts; gcur[s0 + 3] = ts; }
}

// ---------------------------------------------------------------------------
// f32 -> bf16 table, vectorized 4 at a time
// ---------------------------------------------------------------------------
__global__ void conv_bf16_kernel(const float* __restrict__ in,
                                 unsigned short* __restrict__ outb, long long n4) {
    long long i = (long long)blockIdx.x * blockDim.x + threadIdx.x;
    long long stride = (long long)gridDim.x * blockDim.x;
    for (; i < n4; i += stride) {
        float4 f = reinterpret_cast<const float4*>(in)[i];
        ushort4 o;
        o.x = f2bf(f.x); o.y = f2bf(f.y); o.z = f2bf(f.z); o.w = f2bf(f.w);
        reinterpret_cast<ushort4*>(outb)[i] = o;
    }
}

// ---------------------------------------------------------------------------
// Pass 1: tile-local LDS bucket sort, then append contiguous runs to bins.
// ---------------------------------------------------------------------------
__global__ void __launch_bounds__(256, 2) binscatter_kernel(
        const int* __restrict__ rows, const int* __restrict__ cols,
        const float* __restrict__ vals, int* __restrict__ gcur,
        int2* __restrict__ tmp, int E, int nsub) {
    __shared__ int hist[NSUB_PAD];
    __shared__ int base[NSUB_PAD];
    __shared__ int gbase[NSUB_PAD];
    __shared__ int2 stage[TILE];
    __shared__ int sc[256];
    int t = threadIdx.x;
    int tb = blockIdx.x * TILE;
    int tilecnt = E - tb; if (tilecnt > TILE) tilecnt = TILE;

    for (int i = t; i < NSUB_PAD; i += 256) hist[i] = 0;
    __syncthreads();
    #pragma unroll
    for (int k = 0; k < TILE / 256; ++k) {
        int e = tb + k * 256 + t;
        if (e < E) atomicAdd(&hist[rows[e] >> SUB_SHIFT], 1);
    }
    __syncthreads();
    int c0 = hist[4 * t], c1 = hist[4 * t + 1], c2 = hist[4 * t + 2], c3 = hist[4 * t + 3];
    int csum = c0 + c1 + c2 + c3;
    sc[t] = csum;
    __syncthreads();
    for (int o = 1; o < 256; o <<= 1) {
        int u = (t >= o) ? sc[t - o] : 0;
        __syncthreads();
        sc[t] += u;
        __syncthreads();
    }
    int ex = sc[t] - csum;
    base[4 * t] = ex;
    base[4 * t + 1] = ex + c0;
    base[4 * t + 2] = ex + c0 + c1;
    base[4 * t + 3] = ex + c0 + c1 + c2;
    __syncthreads();
    for (int i = t; i < NSUB_PAD; i += 256) hist[i] = 0;
    __syncthreads();
    #pragma unroll
    for (int k = 0; k < TILE / 256; ++k) {
        int e = tb + k * 256 + t;
        if (e < E) {
            int r = rows[e];
            int b = r >> SUB_SHIFT;
            int pos = base[b] + atomicAdd(&hist[b], 1);
            stage[pos] = make_int2(cols[e] | ((r & (SUB_ROWS - 1)) << COLBITS),
                                   __float_as_int(vals[e]));
        }
    }
    __syncthreads();
    for (int i = t; i < nsub; i += 256) {
        int n = hist[i];
        int gb = 0;
        if (n > 0) gb = atomicAdd(&gcur[i], n);
        gbase[i] = gb - base[i];
    }
    __syncthreads();
    for (int p = t; p < tilecnt; p += 256) {
        int lo = 0, hi = nsub;
        while (hi - lo > 1) { int mid = (lo + hi) >> 1; if (base[mid] <= p) lo = mid; else hi = mid; }
        tmp[gbase[lo] + p] = stage[p];
    }
}

// ---------------------------------------------------------------------------
// Pass 2: one block per sub-bucket -> offcnt (int2 per row), sorted spair.
// ---------------------------------------------------------------------------
__global__ void subsort_kernel(const int2* __restrict__ tmp, const int* __restrict__ tstart,
                               const int* __restrict__ stot, const int* __restrict__ csr0,
                               int2* __restrict__ oc, int2* __restrict__ spair, int N) {
    __shared__ int lcnt[SUB_ROWS], lpos[SUB_ROWS], lcur[SUB_ROWS];
    int s = blockIdx.x;
    int t = threadIdx.x;
    int beg = tstart[s], n = stot[s], c0 = csr0[s];
    if (t < SUB_ROWS) lcnt[t] = 0;
    __syncthreads();
    for (int i = t; i < n; i += blockDim.x)
        atomicAdd(&lcnt[(tmp[beg + i].x >> COLBITS) & (SUB_ROWS - 1)], 1);
    __syncthreads();
    if (t < SUB_ROWS) lpos[t] = lcnt[t];
    __syncthreads();
    for (int o = 1; o < SUB_ROWS; o <<= 1) {
        int u = (t < SUB_ROWS && t >= o) ? lpos[t - o] : 0;
        __syncthreads();
        if (t < SUB_ROWS) lpos[t] += u;
        __syncthreads();
    }
    if (t < SUB_ROWS) {
        int excl = lpos[t] - lcnt[t];
        lcur[t] = excl;
        int row = (s << SUB_SHIFT) + t;
        if (row < N) oc[row] = make_int2(c0 + excl, lcnt[t]);
    }
    __syncthreads();
    for (int i = t; i < n; i += blockDim.x) {
        int2 w = tmp[beg + i];
        int rl = (w.x >> COLBITS) & (SUB_ROWS - 1);
        int p = atomicAdd(&lcur[rl], 1);
        spair[c0 + p] = make_int2(w.x & COL_MASK, w.y);
    }
}

// ---------------------------------------------------------------------------
// Gather hops: one wave per row; lane l -> features {2*(l&31), 2*(l&31)+1}
// of edge-slot (l>>5). Per 2 edges: one dwordx2 load (per-half address, no
// cndmask) + one 32-bit-indexed ushort2 gather per lane. shfl_xor(32) combine.
// ---------------------------------------------------------------------------

#define GATHER_CORE(TBL)                                                        \
    int el = lane >> 5;                                                         \
    int f  = lane & 31;                                                         \
    const unsigned* tb = (const unsigned*)(TBL);                                \
    const int2* sp = spair + el;      /* half-wave edge pointer */              \
    float acc0 = 0.f, acc1 = 0.f;                                               \
    for (; e + 8 <= end; e += 8) {                                              \
        int2 wa = sp[e];     int2 wb = sp[e + 2];                               \
        int2 wc = sp[e + 4]; int2 wd = sp[e + 6];                               \
        unsigned pa = tb[(unsigned)wa.x * 32u + (unsigned)f];                   \
        unsigned pb = tb[(unsigned)wb.x * 32u + (unsigned)f];                   \
        unsigned pc = tb[(unsigned)wc.x * 32u + (unsigned)f];                   \
        unsigned pd = tb[(unsigned)wd.x * 32u + (unsigned)f];                   \
        float va = __int_as_float(wa.y), vb = __int_as_float(wb.y);             \
        float vc = __int_as_float(wc.y), vd = __int_as_float(wd.y);             \
        acc0 += va * __uint_as_float(pa << 16);                                 \
        acc1 += va * __uint_as_float(pa & 0xFFFF0000u);                         \
        acc0 += vb * __uint_as_float(pb << 16);                                 \
        acc1 += vb * __uint_as_float(pb & 0xFFFF0000u);                         \
        acc0 += vc * __uint_as_float(pc << 16);                                 \
        acc1 += vc * __uint_as_float(pc & 0xFFFF0000u);                         \
        acc0 += vd * __uint_as_float(pd << 16);                                 \
        acc1 += vd * __uint_as_float(pd & 0xFFFF0000u);                         \
    }                                                                           \
    for (; e + 2 <= end; e += 2) {                                              \
        int2 w = sp[e];                                                         \
        unsigned pk = tb[(unsigned)w.x * 32u + (unsigned)f];                    \
        float v = __int_as_float(w.y);                                          \
        acc0 += v * __uint_as_float(pk << 16);                                  \
        acc1 += v * __uint_as_float(pk & 0xFFFF0000u);                          \
    }                                                                           \
    if (e < end) {                                                              \
        int2 w = spair[e];                                                      \
        float v = el ? 0.f : __int_as_float(w.y);                               \
        unsigned pk = tb[(unsigned)w.x * 32u + (unsigned)f];                    \
        acc0 += v * __uint_as_float(pk << 16);                                  \
        acc1 += v * __uint_as_float(pk & 0xFFFF0000u);                          \
    }                                                                           \
    acc0 += __shfl_xor(acc0, 32);                                               \
    acc1 += __shfl_xor(acc1, 32);

__global__ void __launch_bounds__(256) spmm_gather1_kernel(
        const int2* __restrict__ oc, const int2* __restrict__ spair,
        const unsigned short* __restrict__ xb, unsigned short* __restrict__ axb, int N) {
    int wid = blockIdx.x * (blockDim.x >> 6) + (threadIdx.x >> 6);
    int lane = threadIdx.x & 63;
    if (wid >= N) return;
    int2 o = oc[wid];
    int e = o.x, end = o.x + o.y;
    GATHER_CORE(xb)
    if (el == 0) {
        unsigned pk = (unsigned)f2bf(acc0) | ((unsigned)f2bf(acc1) << 16);
        ((unsigned*)axb)[(size_t)wid * 32 + f] = pk;
    }
}

__global__ void __launch_bounds__(256) spmm_gather2_kernel(
        const int2* __restrict__ oc, const int2* __restrict__ spair,
        const unsigned short* __restrict__ axb, const float* __restrict__ alpha,
        const float* __restrict__ x, float* __restrict__ out, int N) {
    int wid = blockIdx.x * (blockDim.x >> 6) + (threadIdx.x >> 6);
    int lane = threadIdx.x & 63;
    if (wid >= N) return;
    int2 o = oc[wid];
    int e = o.x, end = o.x + o.y;
    GATHER_CORE(axb)
    if (el == 0) {
        float a = 1.0f / (1.0f + __expf(-alpha[wid]));
        float2 xv = ((const float2*)x)[(size_t)wid * 32 + f];
        float2 ov;
        ov.x = a * acc0 - xv.x;
        ov.y = a * acc1 - xv.y;
        ((float2*)out)[(size_t)wid * 32 + f] = ov;
    }
}

// ---------------------------------------------------------------------------
// Fallback: atomic scatter path (if workspace too small)
// ---------------------------------------------------------------------------
__global__ void spmm_atomic_kernel(const int* __restrict__ rows, const int* __restrict__ cols,
                                   const float* __restrict__ vals, const float* __restrict__ x,
                                   float* __restrict__ y, int E) {
    long long tid = (long long)blockIdx.x * blockDim.x + threadIdx.x;
    long long total = (long long)E * 16;
    long long stride = (long long)gridDim.x * blockDim.x;
    for (; tid < total; tid += stride) {
        int e = (int)(tid >> 4);
        int q = (int)(tid & 15);
        int r = rows[e];
        int c = cols[e];
        float v = vals[e];
        float4 xv = reinterpret_cast<const float4*>(x)[(size_t)c * 16 + q];
        float* yp = y + (size_t)r * LATENT + q * 4;
        atomicAdd(yp + 0, v * xv.x);
        atomicAdd(yp + 1, v * xv.y);
        atomicAdd(yp + 2, v * xv.z);
        atomicAdd(yp + 3, v * xv.w);
    }
}

__global__ void finalize_kernel(const float* __restrict__ alpha, const float* __restrict__ x,
                                float* __restrict__ out, int N) {
    long long tid = (long long)blockIdx.x * blockDim.x + threadIdx.x;
    long long total = (long long)N * 16;
    long long stride = (long long)gridDim.x * blockDim.x;
    for (; tid < total; tid += stride) {
        int i = (int)(tid >> 4);
        float a = 1.0f / (1.0f + __expf(-alpha[i]));
        float4 ov = reinterpret_cast<float4*>(out)[tid];
        float4 xv = reinterpret_cast<const float4*>(x)[tid];
        ov.x = a * ov.x - xv.x;
        ov.y = a * ov.y - xv.y;
        ov.z = a * ov.z - xv.z;
        ov.w = a * ov.w - xv.w;
        reinterpret_cast<float4*>(out)[tid] = ov;
    }
}

// ---------------------------------------------------------------------------

extern "C" void kernel_launch(void* const* d_in, const int* in_sizes, int n_in,
                              void* d_out, int out_size, void* d_ws, size_t ws_size,
                              hipStream_t stream) {
    // setup_inputs order: t, x, alpha_train, edge_rows, edge_cols, edge_vals
    const float* x     = (const float*)d_in[1];
    const float* alpha = (const float*)d_in[2];
    const int*   rows  = (const int*)d_in[3];
    const int*   cols  = (const int*)d_in[4];
    const float* vals  = (const float*)d_in[5];

    const int N = in_sizes[2];   // 100000
    const int E = in_sizes[3];   // 3200000
    float* out = (float*)d_out;

    const int block = 256;
    const int nsub   = (N + SUB_ROWS - 1) >> SUB_SHIFT;   // 782
    const int ntiles = (E + TILE - 1) / TILE;             // 391

    auto align256 = [](size_t v) { return (v + 255) & ~(size_t)255; };

    // Region A: tmp (bin-sorted edges, alive through subsort), then reused
    // for xbf (bf16 x) + axbf (bf16 ax1).
    size_t tmp_bytes  = ((size_t)E + 8 * (size_t)nsub) * sizeof(int2);
    size_t xbf_bytes  = (size_t)N * LATENT * sizeof(unsigned short);
    size_t o_axbf_inA = align256(xbf_bytes);
    size_t bf_bytes   = o_axbf_inA + xbf_bytes;
    size_t RA = tmp_bytes > bf_bytes ? tmp_bytes : bf_bytes;

    size_t o_tmp    = 0;
    size_t o_spair  = align256(o_tmp + RA);
    size_t o_oc     = align256(o_spair + (size_t)E * sizeof(int2));
    size_t o_csr0   = align256(o_oc + (size_t)N * sizeof(int2));
    size_t o_tstart = align256(o_csr0 + (size_t)nsub * sizeof(int));
    size_t o_stot   = align256(o_tstart + (size_t)nsub * sizeof(int));
    size_t o_gcur   = align256(o_stot + (size_t)nsub * sizeof(int));
    size_t o_tot    = align256(o_gcur + (size_t)nsub * sizeof(int));
    size_t needed   = o_tot + (size_t)nsub * sizeof(int);
    size_t part_bytes = (size_t)HIST_BLOCKS * nsub * sizeof(int);

    if (ws_size >= needed && nsub <= NSUB_PAD && N <= (1 << COLBITS) &&
        part_bytes <= (size_t)E * sizeof(int2)) {
        char* ws = (char*)d_ws;
        int2*           tmp    = (int2*)(ws + o_tmp);
        unsigned short* xbf    = (unsigned short*)(ws + o_tmp);          // after subsort
        unsigned short* axbf   = (unsigned short*)(ws + o_tmp + o_axbf_inA);
        int2*           spair  = (int2*)(ws + o_spair);
        int*            part   = (int*)(ws + o_spair);   // aliases spair (earlier lifetime)
        int2*           oc     = (int2*)(ws + o_oc);
        int*            csr0   = (int*)(ws + o_csr0);
        int*            tstart = (int*)(ws + o_tstart);
        int*            stot   = (int*)(ws + o_stot);
        int*            gcur   = (int*)(ws + o_gcur);
        int*            tot    = (int*)(ws + o_tot);

        // CSR-bucket metadata
        subhist_kernel<<<HIST_BLOCKS, 256, 0, stream>>>(rows, part, E, nsub);
        reduce_partials_kernel<<<nsub, 256, 0, stream>>>(part, tot, nsub, HIST_BLOCKS);
        subscan_kernel<<<1, 256, 0, stream>>>(tot, csr0, tstart, stot, gcur, nsub);

        // Bin + sort edges into CSR order
        binscatter_kernel<<<ntiles, 256, 0, stream>>>(rows, cols, vals, gcur, tmp, E, nsub);
        subsort_kernel<<<nsub, 256, 0, stream>>>(tmp, tstart, stot, csr0, oc, spair, N);

        // tmp dead -> build bf16 x table in its region
        long long n4 = (long long)N * (LATENT / 4);
        conv_bf16_kernel<<<2048, 256, 0, stream>>>(x, xbf, n4);

        // Two gather hops (wave per row), packed bf16x2 lanes
        int rows_per_block = block / 64;
        int grid_rows = (N + rows_per_block - 1) / rows_per_block;
        spmm_gather1_kernel<<<grid_rows, block, 0, stream>>>(oc, spair, xbf, axbf, N);
        spmm_gather2_kernel<<<grid_rows, block, 0, stream>>>(oc, spair, axbf,
                                                             alpha, x, out, N);
        return;
    }

    // Fallback: atomic scatter path
    {
        float* ax1 = (float*)d_ws;
        const size_t feat_bytes = (size_t)N * LATENT * sizeof(float);
        hipMemsetAsync(ax1, 0, feat_bytes, stream);
        hipMemsetAsync(out, 0, feat_bytes, stream);
        long long work = (long long)E * 16;
        int grid_spmm = (int)((work + block - 1) / block);
        spmm_atomic_kernel<<<grid_spmm, block, 0, stream>>>(rows, cols, vals, x, ax1, E);
        spmm_atomic_kernel<<<grid_spmm, block, 0, stream>>>(rows, cols, vals, ax1, out, E);
        long long fwork = (long long)N * 16;
        int grid_fin = (int)((fwork + block - 1) / block);
        finalize_kernel<<<grid_fin, block, 0, stream>>>(alpha, x, out, N);
    }
}

// Round 11
// 247.531 us; speedup vs baseline: 11.2363x; 1.1328x over previous
//
#include <hip/hip_runtime.h>

#define LATENT 64
#define SUB_SHIFT 7
#define SUB_ROWS 128
#define COLBITS 17
#define COL_MASK ((1 << COLBITS) - 1)
#define HIST_BLOCKS 256
#define TILE 8192
#define NSUB_PAD 1024

__device__ __forceinline__ unsigned short f2bf(float f) {
    unsigned u = __float_as_uint(f);
    unsigned r = (u + 0x7FFFu + ((u >> 16) & 1u)) >> 16;   // round-nearest-even
    return (unsigned short)r;
}

// ---------------------------------------------------------------------------
// Kernel A: per-block sub-bucket histogram partials (no global atomics)
// ---------------------------------------------------------------------------
__global__ void subhist_kernel(const int* __restrict__ rows, int* __restrict__ part,
                               int E, int nsub) {
    __shared__ int h[NSUB_PAD];
    int t = threadIdx.x;
    for (int i = t; i < NSUB_PAD; i += blockDim.x) h[i] = 0;
    __syncthreads();
    for (int e = blockIdx.x * blockDim.x + t; e < E; e += gridDim.x * blockDim.x)
        atomicAdd(&h[rows[e] >> SUB_SHIFT], 1);
    __syncthreads();
    for (int i = t; i < nsub; i += blockDim.x) part[blockIdx.x * nsub + i] = h[i];
}

// ---------------------------------------------------------------------------
// Kernel A2: parallel reduction of partials -> tot[s]. One block per sub-bucket.
// ---------------------------------------------------------------------------
__global__ void reduce_partials_kernel(const int* __restrict__ part, int* __restrict__ tot,
                                       int nsub, int nblk) {
    __shared__ int s[256];
    int sidx = blockIdx.x;
    int t = threadIdx.x;
    int acc = 0;
    for (int b = t; b < nblk; b += 256) acc += part[b * nsub + sidx];
    s[t] = acc;
    __syncthreads();
    for (int o = 128; o > 0; o >>= 1) {
        if (t < o) s[t] += s[t + o];
        __syncthreads();
    }
    if (t == 0) tot[sidx] = s[0];
}

// ---------------------------------------------------------------------------
// Kernel B (1 block): exclusive scan of tot -> csr0, tstart, stot, gcur
// ---------------------------------------------------------------------------
__global__ void subscan_kernel(const int* __restrict__ tot_in, int* __restrict__ csr0,
                               int* __restrict__ tstart, int* __restrict__ stot,
                               int* __restrict__ gcur, int nsub) {
    __shared__ int tot[NSUB_PAD];
    __shared__ int sc[256];
    int t = threadIdx.x;
    for (int i = t; i < NSUB_PAD; i += 256) tot[i] = (i < nsub) ? tot_in[i] : 0;
    __syncthreads();
    int c0 = tot[4 * t], c1 = tot[4 * t + 1], c2 = tot[4 * t + 2], c3 = tot[4 * t + 3];
    int csum = c0 + c1 + c2 + c3;
    sc[t] = csum;
    __syncthreads();
    for (int o = 1; o < 256; o <<= 1) {
        int u = (t >= o) ? sc[t - o] : 0;
        __syncthreads();
        sc[t] += u;
        __syncthreads();
    }
    int pre = sc[t] - csum;   // exclusive chunk base
    int s0 = 4 * t;
    if (s0 < nsub)     { csr0[s0] = pre;     stot[s0] = c0;     int ts = pre + 8 * s0;       tstart[s0] = ts;     gcur[s0] = ts; }
    pre += c0;
    if (s0 + 1 < nsub) { csr0[s0 + 1] = pre; stot[s0 + 1] = c1; int ts = pre + 8 * (s0 + 1); tstart[s0 + 1] = ts; gcur[s0 + 1] = ts; }
    pre += c1;
    if (s0 + 2 < nsub) { csr0[s0 + 2] = pre; stot[s0 + 2] = c2; int ts = pre + 8 * (s0 + 2); tstart[s0 + 2] = ts; gcur[s0 + 2] = ts; }
    pre += c2;
    if (s0 + 3 < nsub) { csr0[s0 + 3] = pre; stot[s0 + 3] = c3; int ts = pre + 8 * (s0 + 3); tstart[s0 + 3] = ts; gcur[s0 + 3] = ts; }
}

// ---------------------------------------------------------------------------
// f32 -> bf16 table, vectorized 4 at a time
// ---------------------------------------------------------------------------
__global__ void conv_bf16_kernel(const float* __restrict__ in,
                                 unsigned short* __restrict__ outb, long long n4) {
    long long i = (long long)blockIdx.x * blockDim.x + threadIdx.x;
    long long stride = (long long)gridDim.x * blockDim.x;
    for (; i < n4; i += stride) {
        float4 f = reinterpret_cast<const float4*>(in)[i];
        ushort4 o;
        o.x = f2bf(f.x); o.y = f2bf(f.y); o.z = f2bf(f.z); o.w = f2bf(f.w);
        reinterpret_cast<ushort4*>(outb)[i] = o;
    }
}

// ---------------------------------------------------------------------------
// Pass 1: tile-local LDS bucket sort, then append contiguous runs to bins.
// ---------------------------------------------------------------------------
__global__ void __launch_bounds__(256, 2) binscatter_kernel(
        const int* __restrict__ rows, const int* __restrict__ cols,
        const float* __restrict__ vals, int* __restrict__ gcur,
        int2* __restrict__ tmp, int E, int nsub) {
    __shared__ int hist[NSUB_PAD];
    __shared__ int base[NSUB_PAD];
    __shared__ int gbase[NSUB_PAD];
    __shared__ int2 stage[TILE];
    __shared__ int sc[256];
    int t = threadIdx.x;
    int tb = blockIdx.x * TILE;
    int tilecnt = E - tb; if (tilecnt > TILE) tilecnt = TILE;

    for (int i = t; i < NSUB_PAD; i += 256) hist[i] = 0;
    __syncthreads();
    #pragma unroll
    for (int k = 0; k < TILE / 256; ++k) {
        int e = tb + k * 256 + t;
        if (e < E) atomicAdd(&hist[rows[e] >> SUB_SHIFT], 1);
    }
    __syncthreads();
    int c0 = hist[4 * t], c1 = hist[4 * t + 1], c2 = hist[4 * t + 2], c3 = hist[4 * t + 3];
    int csum = c0 + c1 + c2 + c3;
    sc[t] = csum;
    __syncthreads();
    for (int o = 1; o < 256; o <<= 1) {
        int u = (t >= o) ? sc[t - o] : 0;
        __syncthreads();
        sc[t] += u;
        __syncthreads();
    }
    int ex = sc[t] - csum;
    base[4 * t] = ex;
    base[4 * t + 1] = ex + c0;
    base[4 * t + 2] = ex + c0 + c1;
    base[4 * t + 3] = ex + c0 + c1 + c2;
    __syncthreads();
    for (int i = t; i < NSUB_PAD; i += 256) hist[i] = 0;
    __syncthreads();
    #pragma unroll
    for (int k = 0; k < TILE / 256; ++k) {
        int e = tb + k * 256 + t;
        if (e < E) {
            int r = rows[e];
            int b = r >> SUB_SHIFT;
            int pos = base[b] + atomicAdd(&hist[b], 1);
            stage[pos] = make_int2(cols[e] | ((r & (SUB_ROWS - 1)) << COLBITS),
                                   __float_as_int(vals[e]));
        }
    }
    __syncthreads();
    for (int i = t; i < nsub; i += 256) {
        int n = hist[i];
        int gb = 0;
        if (n > 0) gb = atomicAdd(&gcur[i], n);
        gbase[i] = gb - base[i];
    }
    __syncthreads();
    for (int p = t; p < tilecnt; p += 256) {
        int lo = 0, hi = nsub;
        while (hi - lo > 1) { int mid = (lo + hi) >> 1; if (base[mid] <= p) lo = mid; else hi = mid; }
        tmp[gbase[lo] + p] = stage[p];
    }
}

// ---------------------------------------------------------------------------
// Pass 2: one block per sub-bucket -> offcnt (int2 per row), sorted spair.
// ---------------------------------------------------------------------------
__global__ void subsort_kernel(const int2* __restrict__ tmp, const int* __restrict__ tstart,
                               const int* __restrict__ stot, const int* __restrict__ csr0,
                               int2* __restrict__ oc, int2* __restrict__ spair, int N) {
    __shared__ int lcnt[SUB_ROWS], lpos[SUB_ROWS], lcur[SUB_ROWS];
    int s = blockIdx.x;
    int t = threadIdx.x;
    int beg = tstart[s], n = stot[s], c0 = csr0[s];
    if (t < SUB_ROWS) lcnt[t] = 0;
    __syncthreads();
    for (int i = t; i < n; i += blockDim.x)
        atomicAdd(&lcnt[(tmp[beg + i].x >> COLBITS) & (SUB_ROWS - 1)], 1);
    __syncthreads();
    if (t < SUB_ROWS) lpos[t] = lcnt[t];
    __syncthreads();
    for (int o = 1; o < SUB_ROWS; o <<= 1) {
        int u = (t < SUB_ROWS && t >= o) ? lpos[t - o] : 0;
        __syncthreads();
        if (t < SUB_ROWS) lpos[t] += u;
        __syncthreads();
    }
    if (t < SUB_ROWS) {
        int excl = lpos[t] - lcnt[t];
        lcur[t] = excl;
        int row = (s << SUB_SHIFT) + t;
        if (row < N) oc[row] = make_int2(c0 + excl, lcnt[t]);
    }
    __syncthreads();
    for (int i = t; i < n; i += blockDim.x) {
        int2 w = tmp[beg + i];
        int rl = (w.x >> COLBITS) & (SUB_ROWS - 1);
        int p = atomicAdd(&lcur[rl], 1);
        spair[c0 + p] = make_int2(w.x & COL_MASK, w.y);
    }
}

// ---------------------------------------------------------------------------
// Gather hops: one wave per row; lane l -> features {4f..4f+3} (f=l&15) of
// edge-slot (l>>4). Per 4 edges: one per-lane int2 spair load + one 8B uint2
// gather (512B/instr). Combine via shfl_xor(16)+shfl_xor(32). f32 accumulate.
// ---------------------------------------------------------------------------

#define GATHER_GROUP(EPTR, EIDX)                                                \
    {                                                                           \
        int2 w_ = (EPTR)[EIDX];                                                 \
        uint2 g_ = tb2[(unsigned)w_.x * 16u + (unsigned)f];                     \
        float v_ = __int_as_float(w_.y);                                        \
        acc0 += v_ * __uint_as_float(g_.x << 16);                               \
        acc1 += v_ * __uint_as_float(g_.x & 0xFFFF0000u);                       \
        acc2 += v_ * __uint_as_float(g_.y << 16);                               \
        acc3 += v_ * __uint_as_float(g_.y & 0xFFFF0000u);                       \
    }

#define GATHER_CORE(TBL)                                                        \
    int el = lane >> 4;                                                         \
    int f  = lane & 15;                                                         \
    const uint2* tb2 = (const uint2*)(TBL);                                     \
    const int2* sp = spair + el;      /* quarter-wave edge pointer */           \
    float acc0 = 0.f, acc1 = 0.f, acc2 = 0.f, acc3 = 0.f;                       \
    for (; e + 16 <= end; e += 16) {                                            \
        GATHER_GROUP(sp, e)                                                     \
        GATHER_GROUP(sp, e + 4)                                                 \
        GATHER_GROUP(sp, e + 8)                                                 \
        GATHER_GROUP(sp, e + 12)                                                \
    }                                                                           \
    for (; e + 4 <= end; e += 4) {                                              \
        GATHER_GROUP(sp, e)                                                     \
    }                                                                           \
    if (e < end) {                                                              \
        int ei = e + el;                                                        \
        int ci = ei < end ? ei : end - 1;                                       \
        int2 w_ = spair[ci];                                                    \
        uint2 g_ = tb2[(unsigned)w_.x * 16u + (unsigned)f];                     \
        float v_ = (ei < end) ? __int_as_float(w_.y) : 0.f;                     \
        acc0 += v_ * __uint_as_float(g_.x << 16);                               \
        acc1 += v_ * __uint_as_float(g_.x & 0xFFFF0000u);                       \
        acc2 += v_ * __uint_as_float(g_.y << 16);                               \
        acc3 += v_ * __uint_as_float(g_.y & 0xFFFF0000u);                       \
    }                                                                           \
    acc0 += __shfl_xor(acc0, 16); acc0 += __shfl_xor(acc0, 32);                 \
    acc1 += __shfl_xor(acc1, 16); acc1 += __shfl_xor(acc1, 32);                 \
    acc2 += __shfl_xor(acc2, 16); acc2 += __shfl_xor(acc2, 32);                 \
    acc3 += __shfl_xor(acc3, 16); acc3 += __shfl_xor(acc3, 32);

__global__ void __launch_bounds__(256) spmm_gather1_kernel(
        const int2* __restrict__ oc, const int2* __restrict__ spair,
        const unsigned short* __restrict__ xb, unsigned short* __restrict__ axb, int N) {
    int wid = blockIdx.x * (blockDim.x >> 6) + (threadIdx.x >> 6);
    int lane = threadIdx.x & 63;
    if (wid >= N) return;
    int2 o = oc[wid];
    int e = o.x, end = o.x + o.y;
    GATHER_CORE(xb)
    if (el == 0) {
        uint2 pk;
        pk.x = (unsigned)f2bf(acc0) | ((unsigned)f2bf(acc1) << 16);
        pk.y = (unsigned)f2bf(acc2) | ((unsigned)f2bf(acc3) << 16);
        ((uint2*)axb)[(size_t)wid * 16 + f] = pk;
    }
}

__global__ void __launch_bounds__(256) spmm_gather2_kernel(
        const int2* __restrict__ oc, const int2* __restrict__ spair,
        const unsigned short* __restrict__ axb, const float* __restrict__ alpha,
        const float* __restrict__ x, float* __restrict__ out, int N) {
    int wid = blockIdx.x * (blockDim.x >> 6) + (threadIdx.x >> 6);
    int lane = threadIdx.x & 63;
    if (wid >= N) return;
    int2 o = oc[wid];
    int e = o.x, end = o.x + o.y;
    GATHER_CORE(axb)
    if (el == 0) {
        float a = 1.0f / (1.0f + __expf(-alpha[wid]));
        float4 xv = ((const float4*)x)[(size_t)wid * 16 + f];
        float4 ov;
        ov.x = a * acc0 - xv.x;
        ov.y = a * acc1 - xv.y;
        ov.z = a * acc2 - xv.z;
        ov.w = a * acc3 - xv.w;
        ((float4*)out)[(size_t)wid * 16 + f] = ov;
    }
}

// ---------------------------------------------------------------------------
// Fallback: atomic scatter path (if workspace too small)
// ---------------------------------------------------------------------------
__global__ void spmm_atomic_kernel(const int* __restrict__ rows, const int* __restrict__ cols,
                                   const float* __restrict__ vals, const float* __restrict__ x,
                                   float* __restrict__ y, int E) {
    long long tid = (long long)blockIdx.x * blockDim.x + threadIdx.x;
    long long total = (long long)E * 16;
    long long stride = (long long)gridDim.x * blockDim.x;
    for (; tid < total; tid += stride) {
        int e = (int)(tid >> 4);
        int q = (int)(tid & 15);
        int r = rows[e];
        int c = cols[e];
        float v = vals[e];
        float4 xv = reinterpret_cast<const float4*>(x)[(size_t)c * 16 + q];
        float* yp = y + (size_t)r * LATENT + q * 4;
        atomicAdd(yp + 0, v * xv.x);
        atomicAdd(yp + 1, v * xv.y);
        atomicAdd(yp + 2, v * xv.z);
        atomicAdd(yp + 3, v * xv.w);
    }
}

__global__ void finalize_kernel(const float* __restrict__ alpha, const float* __restrict__ x,
                                float* __restrict__ out, int N) {
    long long tid = (long long)blockIdx.x * blockDim.x + threadIdx.x;
    long long total = (long long)N * 16;
    long long stride = (long long)gridDim.x * blockDim.x;
    for (; tid < total; tid += stride) {
        int i = (int)(tid >> 4);
        float a = 1.0f / (1.0f + __expf(-alpha[i]));
        float4 ov = reinterpret_cast<float4*>(out)[tid];
        float4 xv = reinterpret_cast<const float4*>(x)[tid];
        ov.x = a * ov.x - xv.x;
        ov.y = a * ov.y - xv.y;
        ov.z = a * ov.z - xv.z;
        ov.w = a * ov.w - xv.w;
        reinterpret_cast<float4*>(out)[tid] = ov;
    }
}

// ---------------------------------------------------------------------------

extern "C" void kernel_launch(void* const* d_in, const int* in_sizes, int n_in,
                              void* d_out, int out_size, void* d_ws, size_t ws_size,
                              hipStream_t stream) {
    // setup_inputs order: t, x, alpha_train, edge_rows, edge_cols, edge_vals
    const float* x     = (const float*)d_in[1];
    const float* alpha = (const float*)d_in[2];
    const int*   rows  = (const int*)d_in[3];
    const int*   cols  = (const int*)d_in[4];
    const float* vals  = (const float*)d_in[5];

    const int N = in_sizes[2];   // 100000
    const int E = in_sizes[3];   // 3200000
    float* out = (float*)d_out;

    const int block = 256;
    const int nsub   = (N + SUB_ROWS - 1) >> SUB_SHIFT;   // 782
    const int ntiles = (E + TILE - 1) / TILE;             // 391

    auto align256 = [](size_t v) { return (v + 255) & ~(size_t)255; };

    // Region A: tmp (bin-sorted edges, alive through subsort), then reused
    // for xbf (bf16 x) + axbf (bf16 ax1).
    size_t tmp_bytes  = ((size_t)E + 8 * (size_t)nsub) * sizeof(int2);
    size_t xbf_bytes  = (size_t)N * LATENT * sizeof(unsigned short);
    size_t o_axbf_inA = align256(xbf_bytes);
    size_t bf_bytes   = o_axbf_inA + xbf_bytes;
    size_t RA = tmp_bytes > bf_bytes ? tmp_bytes : bf_bytes;

    size_t o_tmp    = 0;
    size_t o_spair  = align256(o_tmp + RA);
    size_t o_oc     = align256(o_spair + (size_t)E * sizeof(int2));
    size_t o_csr0   = align256(o_oc + (size_t)N * sizeof(int2));
    size_t o_tstart = align256(o_csr0 + (size_t)nsub * sizeof(int));
    size_t o_stot   = align256(o_tstart + (size_t)nsub * sizeof(int));
    size_t o_gcur   = align256(o_stot + (size_t)nsub * sizeof(int));
    size_t o_tot    = align256(o_gcur + (size_t)nsub * sizeof(int));
    size_t needed   = o_tot + (size_t)nsub * sizeof(int);
    size_t part_bytes = (size_t)HIST_BLOCKS * nsub * sizeof(int);

    if (ws_size >= needed && nsub <= NSUB_PAD && N <= (1 << COLBITS) &&
        part_bytes <= (size_t)E * sizeof(int2)) {
        char* ws = (char*)d_ws;
        int2*           tmp    = (int2*)(ws + o_tmp);
        unsigned short* xbf    = (unsigned short*)(ws + o_tmp);          // after subsort
        unsigned short* axbf   = (unsigned short*)(ws + o_tmp + o_axbf_inA);
        int2*           spair  = (int2*)(ws + o_spair);
        int*            part   = (int*)(ws + o_spair);   // aliases spair (earlier lifetime)
        int2*           oc     = (int2*)(ws + o_oc);
        int*            csr0   = (int*)(ws + o_csr0);
        int*            tstart = (int*)(ws + o_tstart);
        int*            stot   = (int*)(ws + o_stot);
        int*            gcur   = (int*)(ws + o_gcur);
        int*            tot    = (int*)(ws + o_tot);

        // CSR-bucket metadata
        subhist_kernel<<<HIST_BLOCKS, 256, 0, stream>>>(rows, part, E, nsub);
        reduce_partials_kernel<<<nsub, 256, 0, stream>>>(part, tot, nsub, HIST_BLOCKS);
        subscan_kernel<<<1, 256, 0, stream>>>(tot, csr0, tstart, stot, gcur, nsub);

        // Bin + sort edges into CSR order
        binscatter_kernel<<<ntiles, 256, 0, stream>>>(rows, cols, vals, gcur, tmp, E, nsub);
        subsort_kernel<<<nsub, 256, 0, stream>>>(tmp, tstart, stot, csr0, oc, spair, N);

        // tmp dead -> build bf16 x table in its region
        long long n4 = (long long)N * (LATENT / 4);
        conv_bf16_kernel<<<2048, 256, 0, stream>>>(x, xbf, n4);

        // Two gather hops (wave per row), 4 features/lane x 4 edge-slots
        int rows_per_block = block / 64;
        int grid_rows = (N + rows_per_block - 1) / rows_per_block;
        spmm_gather1_kernel<<<grid_rows, block, 0, stream>>>(oc, spair, xbf, axbf, N);
        spmm_gather2_kernel<<<grid_rows, block, 0, stream>>>(oc, spair, axbf,
                                                             alpha, x, out, N);
        return;
    }

    // Fallback: atomic scatter path
    {
        float* ax1 = (float*)d_ws;
        const size_t feat_bytes = (size_t)N * LATENT * sizeof(float);
        hipMemsetAsync(ax1, 0, feat_bytes, stream);
        hipMemsetAsync(out, 0, feat_bytes, stream);
        long long work = (long long)E * 16;
        int grid_spmm = (int)((work + block - 1) / block);
        spmm_atomic_kernel<<<grid_spmm, block, 0, stream>>>(rows, cols, vals, x, ax1, E);
        spmm_atomic_kernel<<<grid_spmm, block, 0, stream>>>(rows, cols, vals, ax1, out, E);
        long long fwork = (long long)N * 16;
        int grid_fin = (int)((fwork + block - 1) / block);
        finalize_kernel<<<grid_fin, block, 0, stream>>>(alpha, x, out, N);
    }
}

// Round 12
// 226.992 us; speedup vs baseline: 12.2530x; 1.0905x over previous
//
#include <hip/hip_runtime.h>

#define LATENT 64
#define SUB_SHIFT 7
#define SUB_ROWS 128
#define COLBITS 17
#define COL_MASK ((1 << COLBITS) - 1)
#define HIST_BLOCKS 256
#define TILE 8192
#define NSUB_PAD 1024

__device__ __forceinline__ unsigned short f2bf(float f) {
    unsigned u = __float_as_uint(f);
    unsigned r = (u + 0x7FFFu + ((u >> 16) & 1u)) >> 16;   // round-nearest-even
    return (unsigned short)r;
}

// ---------------------------------------------------------------------------
// Kernel A: per-block sub-bucket histogram partials (no global atomics)
// ---------------------------------------------------------------------------
__global__ void subhist_kernel(const int* __restrict__ rows, int* __restrict__ part,
                               int E, int nsub) {
    __shared__ int h[NSUB_PAD];
    int t = threadIdx.x;
    for (int i = t; i < NSUB_PAD; i += blockDim.x) h[i] = 0;
    __syncthreads();
    for (int e = blockIdx.x * blockDim.x + t; e < E; e += gridDim.x * blockDim.x)
        atomicAdd(&h[rows[e] >> SUB_SHIFT], 1);
    __syncthreads();
    for (int i = t; i < nsub; i += blockDim.x) part[blockIdx.x * nsub + i] = h[i];
}

// ---------------------------------------------------------------------------
// Kernel A2: parallel reduction of partials -> tot[s]. One block per sub-bucket.
// ---------------------------------------------------------------------------
__global__ void reduce_partials_kernel(const int* __restrict__ part, int* __restrict__ tot,
                                       int nsub, int nblk) {
    __shared__ int s[256];
    int sidx = blockIdx.x;
    int t = threadIdx.x;
    int acc = 0;
    for (int b = t; b < nblk; b += 256) acc += part[b * nsub + sidx];
    s[t] = acc;
    __syncthreads();
    for (int o = 128; o > 0; o >>= 1) {
        if (t < o) s[t] += s[t + o];
        __syncthreads();
    }
    if (t == 0) tot[sidx] = s[0];
}

// ---------------------------------------------------------------------------
// Kernel B (1 block): exclusive scan of tot -> csr0, tstart, stot, gcur
// ---------------------------------------------------------------------------
__global__ void subscan_kernel(const int* __restrict__ tot_in, int* __restrict__ csr0,
                               int* __restrict__ tstart, int* __restrict__ stot,
                               int* __restrict__ gcur, int nsub) {
    __shared__ int tot[NSUB_PAD];
    __shared__ int sc[256];
    int t = threadIdx.x;
    for (int i = t; i < NSUB_PAD; i += 256) tot[i] = (i < nsub) ? tot_in[i] : 0;
    __syncthreads();
    int c0 = tot[4 * t], c1 = tot[4 * t + 1], c2 = tot[4 * t + 2], c3 = tot[4 * t + 3];
    int csum = c0 + c1 + c2 + c3;
    sc[t] = csum;
    __syncthreads();
    for (int o = 1; o < 256; o <<= 1) {
        int u = (t >= o) ? sc[t - o] : 0;
        __syncthreads();
        sc[t] += u;
        __syncthreads();
    }
    int pre = sc[t] - csum;   // exclusive chunk base
    int s0 = 4 * t;
    if (s0 < nsub)     { csr0[s0] = pre;     stot[s0] = c0;     int ts = pre + 8 * s0;       tstart[s0] = ts;     gcur[s0] = ts; }
    pre += c0;
    if (s0 + 1 < nsub) { csr0[s0 + 1] = pre; stot[s0 + 1] = c1; int ts = pre + 8 * (s0 + 1); tstart[s0 + 1] = ts; gcur[s0 + 1] = ts; }
    pre += c1;
    if (s0 + 2 < nsub) { csr0[s0 + 2] = pre; stot[s0 + 2] = c2; int ts = pre + 8 * (s0 + 2); tstart[s0 + 2] = ts; gcur[s0 + 2] = ts; }
    pre += c2;
    if (s0 + 3 < nsub) { csr0[s0 + 3] = pre; stot[s0 + 3] = c3; int ts = pre + 8 * (s0 + 3); tstart[s0 + 3] = ts; gcur[s0 + 3] = ts; }
}

// ---------------------------------------------------------------------------
// f32 -> bf16 table, vectorized 4 at a time
// ---------------------------------------------------------------------------
__global__ void conv_bf16_kernel(const float* __restrict__ in,
                                 unsigned short* __restrict__ outb, long long n4) {
    long long i = (long long)blockIdx.x * blockDim.x + threadIdx.x;
    long long stride = (long long)gridDim.x * blockDim.x;
    for (; i < n4; i += stride) {
        float4 f = reinterpret_cast<const float4*>(in)[i];
        ushort4 o;
        o.x = f2bf(f.x); o.y = f2bf(f.y); o.z = f2bf(f.z); o.w = f2bf(f.w);
        reinterpret_cast<ushort4*>(outb)[i] = o;
    }
}

// ---------------------------------------------------------------------------
// Pass 1: tile-local LDS bucket sort, then append contiguous runs to bins.
// 512 threads (8 waves) with same 78KB LDS -> 16 waves/CU occupancy.
// ---------------------------------------------------------------------------
__global__ void __launch_bounds__(512, 2) binscatter_kernel(
        const int* __restrict__ rows, const int* __restrict__ cols,
        const float* __restrict__ vals, int* __restrict__ gcur,
        int2* __restrict__ tmp, int E, int nsub) {
    __shared__ int hist[NSUB_PAD];
    __shared__ int base[NSUB_PAD];
    __shared__ int gbase[NSUB_PAD];
    __shared__ int2 stage[TILE];
    __shared__ int sc[512];
    int t = threadIdx.x;
    int tb = blockIdx.x * TILE;
    int tilecnt = E - tb; if (tilecnt > TILE) tilecnt = TILE;

    for (int i = t; i < NSUB_PAD; i += 512) hist[i] = 0;
    __syncthreads();
    #pragma unroll
    for (int k = 0; k < TILE / 512; ++k) {
        int e = tb + k * 512 + t;
        if (e < E) atomicAdd(&hist[rows[e] >> SUB_SHIFT], 1);
    }
    __syncthreads();
    // exclusive scan over NSUB_PAD bins, chunk of 2 per thread
    int c0 = hist[2 * t], c1 = hist[2 * t + 1];
    int csum = c0 + c1;
    sc[t] = csum;
    __syncthreads();
    for (int o = 1; o < 512; o <<= 1) {
        int u = (t >= o) ? sc[t - o] : 0;
        __syncthreads();
        sc[t] += u;
        __syncthreads();
    }
    int ex = sc[t] - csum;
    base[2 * t] = ex;
    base[2 * t + 1] = ex + c0;
    __syncthreads();
    for (int i = t; i < NSUB_PAD; i += 512) hist[i] = 0;   // reset as cursors
    __syncthreads();
    #pragma unroll
    for (int k = 0; k < TILE / 512; ++k) {
        int e = tb + k * 512 + t;
        if (e < E) {
            int r = rows[e];
            int b = r >> SUB_SHIFT;
            int pos = base[b] + atomicAdd(&hist[b], 1);
            stage[pos] = make_int2(cols[e] | ((r & (SUB_ROWS - 1)) << COLBITS),
                                   __float_as_int(vals[e]));
        }
    }
    __syncthreads();
    for (int i = t; i < nsub; i += 512) {
        int n = hist[i];
        int gb = 0;
        if (n > 0) gb = atomicAdd(&gcur[i], n);
        gbase[i] = gb - base[i];
    }
    __syncthreads();
    for (int p = t; p < tilecnt; p += 512) {
        int lo = 0, hi = nsub;
        while (hi - lo > 1) { int mid = (lo + hi) >> 1; if (base[mid] <= p) lo = mid; else hi = mid; }
        tmp[gbase[lo] + p] = stage[p];
    }
}

// ---------------------------------------------------------------------------
// Pass 2: one block per sub-bucket -> offcnt (int2 per row), sorted spair.
// ---------------------------------------------------------------------------
__global__ void subsort_kernel(const int2* __restrict__ tmp, const int* __restrict__ tstart,
                               const int* __restrict__ stot, const int* __restrict__ csr0,
                               int2* __restrict__ oc, int2* __restrict__ spair, int N) {
    __shared__ int lcnt[SUB_ROWS], lpos[SUB_ROWS], lcur[SUB_ROWS];
    int s = blockIdx.x;
    int t = threadIdx.x;
    int beg = tstart[s], n = stot[s], c0 = csr0[s];
    if (t < SUB_ROWS) lcnt[t] = 0;
    __syncthreads();
    for (int i = t; i < n; i += blockDim.x)
        atomicAdd(&lcnt[(tmp[beg + i].x >> COLBITS) & (SUB_ROWS - 1)], 1);
    __syncthreads();
    if (t < SUB_ROWS) lpos[t] = lcnt[t];
    __syncthreads();
    for (int o = 1; o < SUB_ROWS; o <<= 1) {
        int u = (t < SUB_ROWS && t >= o) ? lpos[t - o] : 0;
        __syncthreads();
        if (t < SUB_ROWS) lpos[t] += u;
        __syncthreads();
    }
    if (t < SUB_ROWS) {
        int excl = lpos[t] - lcnt[t];
        lcur[t] = excl;
        int row = (s << SUB_SHIFT) + t;
        if (row < N) oc[row] = make_int2(c0 + excl, lcnt[t]);
    }
    __syncthreads();
    for (int i = t; i < n; i += blockDim.x) {
        int2 w = tmp[beg + i];
        int rl = (w.x >> COLBITS) & (SUB_ROWS - 1);
        int p = atomicAdd(&lcur[rl], 1);
        spair[c0 + p] = make_int2(w.x & COL_MASK, w.y);
    }
}

// ---------------------------------------------------------------------------
// Gather hops: one wave per row; lane l -> features {4f..4f+3} (f=l&15) of
// edge-slot (l>>4). Per 4 edges: one per-lane int2 spair load + one 8B uint2
// gather (512B/instr). Combine via shfl_xor(16)+shfl_xor(32). f32 accumulate.
// ---------------------------------------------------------------------------

#define GATHER_GROUP(EPTR, EIDX)                                                \
    {                                                                           \
        int2 w_ = (EPTR)[EIDX];                                                 \
        uint2 g_ = tb2[(unsigned)w_.x * 16u + (unsigned)f];                     \
        float v_ = __int_as_float(w_.y);                                        \
        acc0 += v_ * __uint_as_float(g_.x << 16);                               \
        acc1 += v_ * __uint_as_float(g_.x & 0xFFFF0000u);                       \
        acc2 += v_ * __uint_as_float(g_.y << 16);                               \
        acc3 += v_ * __uint_as_float(g_.y & 0xFFFF0000u);                       \
    }

#define GATHER_CORE(TBL)                                                        \
    int el = lane >> 4;                                                         \
    int f  = lane & 15;                                                         \
    const uint2* tb2 = (const uint2*)(TBL);                                     \
    const int2* sp = spair + el;      /* quarter-wave edge pointer */           \
    float acc0 = 0.f, acc1 = 0.f, acc2 = 0.f, acc3 = 0.f;                       \
    for (; e + 16 <= end; e += 16) {                                            \
        GATHER_GROUP(sp, e)                                                     \
        GATHER_GROUP(sp, e + 4)                                                 \
        GATHER_GROUP(sp, e + 8)                                                 \
        GATHER_GROUP(sp, e + 12)                                                \
    }                                                                           \
    for (; e + 4 <= end; e += 4) {                                              \
        GATHER_GROUP(sp, e)                                                     \
    }                                                                           \
    if (e < end) {                                                              \
        int ei = e + el;                                                        \
        int ci = ei < end ? ei : end - 1;                                       \
        int2 w_ = spair[ci];                                                    \
        uint2 g_ = tb2[(unsigned)w_.x * 16u + (unsigned)f];                     \
        float v_ = (ei < end) ? __int_as_float(w_.y) : 0.f;                     \
        acc0 += v_ * __uint_as_float(g_.x << 16);                               \
        acc1 += v_ * __uint_as_float(g_.x & 0xFFFF0000u);                       \
        acc2 += v_ * __uint_as_float(g_.y << 16);                               \
        acc3 += v_ * __uint_as_float(g_.y & 0xFFFF0000u);                       \
    }                                                                           \
    acc0 += __shfl_xor(acc0, 16); acc0 += __shfl_xor(acc0, 32);                 \
    acc1 += __shfl_xor(acc1, 16); acc1 += __shfl_xor(acc1, 32);                 \
    acc2 += __shfl_xor(acc2, 16); acc2 += __shfl_xor(acc2, 32);                 \
    acc3 += __shfl_xor(acc3, 16); acc3 += __shfl_xor(acc3, 32);

__global__ void __launch_bounds__(256) spmm_gather1_kernel(
        const int2* __restrict__ oc, const int2* __restrict__ spair,
        const unsigned short* __restrict__ xb, unsigned short* __restrict__ axb, int N) {
    int wid = blockIdx.x * (blockDim.x >> 6) + (threadIdx.x >> 6);
    int lane = threadIdx.x & 63;
    if (wid >= N) return;
    int2 o = oc[wid];
    int e = o.x, end = o.x + o.y;
    GATHER_CORE(xb)
    if (el == 0) {
        uint2 pk;
        pk.x = (unsigned)f2bf(acc0) | ((unsigned)f2bf(acc1) << 16);
        pk.y = (unsigned)f2bf(acc2) | ((unsigned)f2bf(acc3) << 16);
        ((uint2*)axb)[(size_t)wid * 16 + f] = pk;
    }
}

__global__ void __launch_bounds__(256) spmm_gather2_kernel(
        const int2* __restrict__ oc, const int2* __restrict__ spair,
        const unsigned short* __restrict__ axb, const float* __restrict__ alpha,
        const float* __restrict__ x, float* __restrict__ out, int N) {
    int wid = blockIdx.x * (blockDim.x >> 6) + (threadIdx.x >> 6);
    int lane = threadIdx.x & 63;
    if (wid >= N) return;
    int2 o = oc[wid];
    int e = o.x, end = o.x + o.y;
    GATHER_CORE(axb)
    if (el == 0) {
        float a = 1.0f / (1.0f + __expf(-alpha[wid]));
        float4 xv = ((const float4*)x)[(size_t)wid * 16 + f];
        float4 ov;
        ov.x = a * acc0 - xv.x;
        ov.y = a * acc1 - xv.y;
        ov.z = a * acc2 - xv.z;
        ov.w = a * acc3 - xv.w;
        ((float4*)out)[(size_t)wid * 16 + f] = ov;
    }
}

// ---------------------------------------------------------------------------
// Fallback: atomic scatter path (if workspace too small)
// ---------------------------------------------------------------------------
__global__ void spmm_atomic_kernel(const int* __restrict__ rows, const int* __restrict__ cols,
                                   const float* __restrict__ vals, const float* __restrict__ x,
                                   float* __restrict__ y, int E) {
    long long tid = (long long)blockIdx.x * blockDim.x + threadIdx.x;
    long long total = (long long)E * 16;
    long long stride = (long long)gridDim.x * blockDim.x;
    for (; tid < total; tid += stride) {
        int e = (int)(tid >> 4);
        int q = (int)(tid & 15);
        int r = rows[e];
        int c = cols[e];
        float v = vals[e];
        float4 xv = reinterpret_cast<const float4*>(x)[(size_t)c * 16 + q];
        float* yp = y + (size_t)r * LATENT + q * 4;
        atomicAdd(yp + 0, v * xv.x);
        atomicAdd(yp + 1, v * xv.y);
        atomicAdd(yp + 2, v * xv.z);
        atomicAdd(yp + 3, v * xv.w);
    }
}

__global__ void finalize_kernel(const float* __restrict__ alpha, const float* __restrict__ x,
                                float* __restrict__ out, int N) {
    long long tid = (long long)blockIdx.x * blockDim.x + threadIdx.x;
    long long total = (long long)N * 16;
    long long stride = (long long)gridDim.x * blockDim.x;
    for (; tid < total; tid += stride) {
        int i = (int)(tid >> 4);
        float a = 1.0f / (1.0f + __expf(-alpha[i]));
        float4 ov = reinterpret_cast<float4*>(out)[tid];
        float4 xv = reinterpret_cast<const float4*>(x)[tid];
        ov.x = a * ov.x - xv.x;
        ov.y = a * ov.y - xv.y;
        ov.z = a * ov.z - xv.z;
        ov.w = a * ov.w - xv.w;
        reinterpret_cast<float4*>(out)[tid] = ov;
    }
}

// ---------------------------------------------------------------------------

extern "C" void kernel_launch(void* const* d_in, const int* in_sizes, int n_in,
                              void* d_out, int out_size, void* d_ws, size_t ws_size,
                              hipStream_t stream) {
    // setup_inputs order: t, x, alpha_train, edge_rows, edge_cols, edge_vals
    const float* x     = (const float*)d_in[1];
    const float* alpha = (const float*)d_in[2];
    const int*   rows  = (const int*)d_in[3];
    const int*   cols  = (const int*)d_in[4];
    const float* vals  = (const float*)d_in[5];

    const int N = in_sizes[2];   // 100000
    const int E = in_sizes[3];   // 3200000
    float* out = (float*)d_out;

    const int block = 256;
    const int nsub   = (N + SUB_ROWS - 1) >> SUB_SHIFT;   // 782
    const int ntiles = (E + TILE - 1) / TILE;             // 391

    auto align256 = [](size_t v) { return (v + 255) & ~(size_t)255; };

    // Region A: tmp (bin-sorted edges, alive through subsort), then reused
    // for xbf (bf16 x) + axbf (bf16 ax1).
    size_t tmp_bytes  = ((size_t)E + 8 * (size_t)nsub) * sizeof(int2);
    size_t xbf_bytes  = (size_t)N * LATENT * sizeof(unsigned short);
    size_t o_axbf_inA = align256(xbf_bytes);
    size_t bf_bytes   = o_axbf_inA + xbf_bytes;
    size_t RA = tmp_bytes > bf_bytes ? tmp_bytes : bf_bytes;

    size_t o_tmp    = 0;
    size_t o_spair  = align256(o_tmp + RA);
    size_t o_oc     = align256(o_spair + (size_t)E * sizeof(int2));
    size_t o_csr0   = align256(o_oc + (size_t)N * sizeof(int2));
    size_t o_tstart = align256(o_csr0 + (size_t)nsub * sizeof(int));
    size_t o_stot   = align256(o_tstart + (size_t)nsub * sizeof(int));
    size_t o_gcur   = align256(o_stot + (size_t)nsub * sizeof(int));
    size_t o_tot    = align256(o_gcur + (size_t)nsub * sizeof(int));
    size_t needed   = o_tot + (size_t)nsub * sizeof(int);
    size_t part_bytes = (size_t)HIST_BLOCKS * nsub * sizeof(int);

    if (ws_size >= needed && nsub <= NSUB_PAD && N <= (1 << COLBITS) &&
        part_bytes <= (size_t)E * sizeof(int2)) {
        char* ws = (char*)d_ws;
        int2*           tmp    = (int2*)(ws + o_tmp);
        unsigned short* xbf    = (unsigned short*)(ws + o_tmp);          // after subsort
        unsigned short* axbf   = (unsigned short*)(ws + o_tmp + o_axbf_inA);
        int2*           spair  = (int2*)(ws + o_spair);
        int*            part   = (int*)(ws + o_spair);   // aliases spair (earlier lifetime)
        int2*           oc     = (int2*)(ws + o_oc);
        int*            csr0   = (int*)(ws + o_csr0);
        int*            tstart = (int*)(ws + o_tstart);
        int*            stot   = (int*)(ws + o_stot);
        int*            gcur   = (int*)(ws + o_gcur);
        int*            tot    = (int*)(ws + o_tot);

        // CSR-bucket metadata
        subhist_kernel<<<HIST_BLOCKS, 256, 0, stream>>>(rows, part, E, nsub);
        reduce_partials_kernel<<<nsub, 256, 0, stream>>>(part, tot, nsub, HIST_BLOCKS);
        subscan_kernel<<<1, 256, 0, stream>>>(tot, csr0, tstart, stot, gcur, nsub);

        // Bin + sort edges into CSR order
        binscatter_kernel<<<ntiles, 512, 0, stream>>>(rows, cols, vals, gcur, tmp, E, nsub);
        subsort_kernel<<<nsub, 256, 0, stream>>>(tmp, tstart, stot, csr0, oc, spair, N);

        // tmp dead -> build bf16 x table in its region
        long long n4 = (long long)N * (LATENT / 4);
        conv_bf16_kernel<<<2048, 256, 0, stream>>>(x, xbf, n4);

        // Two gather hops (wave per row), 4 features/lane x 4 edge-slots
        int rows_per_block = block / 64;
        int grid_rows = (N + rows_per_block - 1) / rows_per_block;
        spmm_gather1_kernel<<<grid_rows, block, 0, stream>>>(oc, spair, xbf, axbf, N);
        spmm_gather2_kernel<<<grid_rows, block, 0, stream>>>(oc, spair, axbf,
                                                             alpha, x, out, N);
        return;
    }

    // Fallback: atomic scatter path
    {
        float* ax1 = (float*)d_ws;
        const size_t feat_bytes = (size_t)N * LATENT * sizeof(float);
        hipMemsetAsync(ax1, 0, feat_bytes, stream);
        hipMemsetAsync(out, 0, feat_bytes, stream);
        long long work = (long long)E * 16;
        int grid_spmm = (int)((work + block - 1) / block);
        spmm_atomic_kernel<<<grid_spmm, block, 0, stream>>>(rows, cols, vals, x, ax1, E);
        spmm_atomic_kernel<<<grid_spmm, block, 0, stream>>>(rows, cols, vals, ax1, out, E);
        long long fwork = (long long)N * 16;
        int grid_fin = (int)((fwork + block - 1) / block);
        finalize_kernel<<<grid_fin, block, 0, stream>>>(alpha, x, out, N);
    }
}

// Round 13
// 211.528 us; speedup vs baseline: 13.1487x; 1.0731x over previous
//
#include <hip/hip_runtime.h>

#define LATENT 64
#define SUB_SHIFT 7
#define SUB_ROWS 128
#define COLBITS 17
#define COL_MASK ((1 << COLBITS) - 1)
#define HIST_BLOCKS 256
#define TILE 8192
#define NSUB_PAD 1024

__device__ __forceinline__ unsigned short f2bf(float f) {
    unsigned u = __float_as_uint(f);
    unsigned r = (u + 0x7FFFu + ((u >> 16) & 1u)) >> 16;   // round-nearest-even
    return (unsigned short)r;
}

// ---------------------------------------------------------------------------
// Kernel A: per-block sub-bucket histogram partials (no global atomics)
// ---------------------------------------------------------------------------
__global__ void subhist_kernel(const int* __restrict__ rows, int* __restrict__ part,
                               int E, int nsub) {
    __shared__ int h[NSUB_PAD];
    int t = threadIdx.x;
    for (int i = t; i < NSUB_PAD; i += blockDim.x) h[i] = 0;
    __syncthreads();
    for (int e = blockIdx.x * blockDim.x + t; e < E; e += gridDim.x * blockDim.x)
        atomicAdd(&h[rows[e] >> SUB_SHIFT], 1);
    __syncthreads();
    for (int i = t; i < nsub; i += blockDim.x) part[blockIdx.x * nsub + i] = h[i];
}

// ---------------------------------------------------------------------------
// Kernel A2: parallel reduction of partials -> tot[s]. One block per sub-bucket.
// ---------------------------------------------------------------------------
__global__ void reduce_partials_kernel(const int* __restrict__ part, int* __restrict__ tot,
                                       int nsub, int nblk) {
    __shared__ int s[256];
    int sidx = blockIdx.x;
    int t = threadIdx.x;
    int acc = 0;
    for (int b = t; b < nblk; b += 256) acc += part[b * nsub + sidx];
    s[t] = acc;
    __syncthreads();
    for (int o = 128; o > 0; o >>= 1) {
        if (t < o) s[t] += s[t + o];
        __syncthreads();
    }
    if (t == 0) tot[sidx] = s[0];
}

// ---------------------------------------------------------------------------
// Kernel B (1 block): exclusive scan of tot -> csr0, tstart, stot, gcur
// ---------------------------------------------------------------------------
__global__ void subscan_kernel(const int* __restrict__ tot_in, int* __restrict__ csr0,
                               int* __restrict__ tstart, int* __restrict__ stot,
                               int* __restrict__ gcur, int nsub) {
    __shared__ int tot[NSUB_PAD];
    __shared__ int sc[256];
    int t = threadIdx.x;
    for (int i = t; i < NSUB_PAD; i += 256) tot[i] = (i < nsub) ? tot_in[i] : 0;
    __syncthreads();
    int c0 = tot[4 * t], c1 = tot[4 * t + 1], c2 = tot[4 * t + 2], c3 = tot[4 * t + 3];
    int csum = c0 + c1 + c2 + c3;
    sc[t] = csum;
    __syncthreads();
    for (int o = 1; o < 256; o <<= 1) {
        int u = (t >= o) ? sc[t - o] : 0;
        __syncthreads();
        sc[t] += u;
        __syncthreads();
    }
    int pre = sc[t] - csum;   // exclusive chunk base
    int s0 = 4 * t;
    if (s0 < nsub)     { csr0[s0] = pre;     stot[s0] = c0;     int ts = pre + 8 * s0;       tstart[s0] = ts;     gcur[s0] = ts; }
    pre += c0;
    if (s0 + 1 < nsub) { csr0[s0 + 1] = pre; stot[s0 + 1] = c1; int ts = pre + 8 * (s0 + 1); tstart[s0 + 1] = ts; gcur[s0 + 1] = ts; }
    pre += c1;
    if (s0 + 2 < nsub) { csr0[s0 + 2] = pre; stot[s0 + 2] = c2; int ts = pre + 8 * (s0 + 2); tstart[s0 + 2] = ts; gcur[s0 + 2] = ts; }
    pre += c2;
    if (s0 + 3 < nsub) { csr0[s0 + 3] = pre; stot[s0 + 3] = c3; int ts = pre + 8 * (s0 + 3); tstart[s0 + 3] = ts; gcur[s0 + 3] = ts; }
}

// ---------------------------------------------------------------------------
// f32 -> bf16 table, vectorized 4 at a time
// ---------------------------------------------------------------------------
__global__ void conv_bf16_kernel(const float* __restrict__ in,
                                 unsigned short* __restrict__ outb, long long n4) {
    long long i = (long long)blockIdx.x * blockDim.x + threadIdx.x;
    long long stride = (long long)gridDim.x * blockDim.x;
    for (; i < n4; i += stride) {
        float4 f = reinterpret_cast<const float4*>(in)[i];
        ushort4 o;
        o.x = f2bf(f.x); o.y = f2bf(f.y); o.z = f2bf(f.z); o.w = f2bf(f.w);
        reinterpret_cast<ushort4*>(outb)[i] = o;
    }
}

// ---------------------------------------------------------------------------
// Pass 1: tile-local LDS bucket sort, then append contiguous runs to bins.
// 512 threads (8 waves) with same 78KB LDS -> 16 waves/CU occupancy.
// ---------------------------------------------------------------------------
__global__ void __launch_bounds__(512, 2) binscatter_kernel(
        const int* __restrict__ rows, const int* __restrict__ cols,
        const float* __restrict__ vals, int* __restrict__ gcur,
        int2* __restrict__ tmp, int E, int nsub) {
    __shared__ int hist[NSUB_PAD];
    __shared__ int base[NSUB_PAD];
    __shared__ int gbase[NSUB_PAD];
    __shared__ int2 stage[TILE];
    __shared__ int sc[512];
    int t = threadIdx.x;
    int tb = blockIdx.x * TILE;
    int tilecnt = E - tb; if (tilecnt > TILE) tilecnt = TILE;

    for (int i = t; i < NSUB_PAD; i += 512) hist[i] = 0;
    __syncthreads();
    #pragma unroll
    for (int k = 0; k < TILE / 512; ++k) {
        int e = tb + k * 512 + t;
        if (e < E) atomicAdd(&hist[rows[e] >> SUB_SHIFT], 1);
    }
    __syncthreads();
    // exclusive scan over NSUB_PAD bins, chunk of 2 per thread
    int c0 = hist[2 * t], c1 = hist[2 * t + 1];
    int csum = c0 + c1;
    sc[t] = csum;
    __syncthreads();
    for (int o = 1; o < 512; o <<= 1) {
        int u = (t >= o) ? sc[t - o] : 0;
        __syncthreads();
        sc[t] += u;
        __syncthreads();
    }
    int ex = sc[t] - csum;
    base[2 * t] = ex;
    base[2 * t + 1] = ex + c0;
    __syncthreads();
    for (int i = t; i < NSUB_PAD; i += 512) hist[i] = 0;   // reset as cursors
    __syncthreads();
    #pragma unroll
    for (int k = 0; k < TILE / 512; ++k) {
        int e = tb + k * 512 + t;
        if (e < E) {
            int r = rows[e];
            int b = r >> SUB_SHIFT;
            int pos = base[b] + atomicAdd(&hist[b], 1);
            stage[pos] = make_int2(cols[e] | ((r & (SUB_ROWS - 1)) << COLBITS),
                                   __float_as_int(vals[e]));
        }
    }
    __syncthreads();
    for (int i = t; i < nsub; i += 512) {
        int n = hist[i];
        int gb = 0;
        if (n > 0) gb = atomicAdd(&gcur[i], n);
        gbase[i] = gb - base[i];
    }
    __syncthreads();
    for (int p = t; p < tilecnt; p += 512) {
        int lo = 0, hi = nsub;
        while (hi - lo > 1) { int mid = (lo + hi) >> 1; if (base[mid] <= p) lo = mid; else hi = mid; }
        tmp[gbase[lo] + p] = stage[p];
    }
}

// ---------------------------------------------------------------------------
// Pass 2: one block per sub-bucket -> offcnt (int2 per row), sorted spair.
// ---------------------------------------------------------------------------
__global__ void subsort_kernel(const int2* __restrict__ tmp, const int* __restrict__ tstart,
                               const int* __restrict__ stot, const int* __restrict__ csr0,
                               int2* __restrict__ oc, int2* __restrict__ spair, int N) {
    __shared__ int lcnt[SUB_ROWS], lpos[SUB_ROWS], lcur[SUB_ROWS];
    int s = blockIdx.x;
    int t = threadIdx.x;
    int beg = tstart[s], n = stot[s], c0 = csr0[s];
    if (t < SUB_ROWS) lcnt[t] = 0;
    __syncthreads();
    for (int i = t; i < n; i += blockDim.x)
        atomicAdd(&lcnt[(tmp[beg + i].x >> COLBITS) & (SUB_ROWS - 1)], 1);
    __syncthreads();
    if (t < SUB_ROWS) lpos[t] = lcnt[t];
    __syncthreads();
    for (int o = 1; o < SUB_ROWS; o <<= 1) {
        int u = (t < SUB_ROWS && t >= o) ? lpos[t - o] : 0;
        __syncthreads();
        if (t < SUB_ROWS) lpos[t] += u;
        __syncthreads();
    }
    if (t < SUB_ROWS) {
        int excl = lpos[t] - lcnt[t];
        lcur[t] = excl;
        int row = (s << SUB_SHIFT) + t;
        if (row < N) oc[row] = make_int2(c0 + excl, lcnt[t]);
    }
    __syncthreads();
    for (int i = t; i < n; i += blockDim.x) {
        int2 w = tmp[beg + i];
        int rl = (w.x >> COLBITS) & (SUB_ROWS - 1);
        int p = atomicAdd(&lcur[rl], 1);
        spair[c0 + p] = make_int2(w.x & COL_MASK, w.y);
    }
}

// ---------------------------------------------------------------------------
// Gather hops: one wave per row; lane l -> features {8f..8f+7} (f=l&7) of
// edge-slot (l>>3). Per 8 edges: one broadcast int2 spair load + one 16B uint4
// gather (1024B/instr = 8 full rows). Combine via shfl_xor(8,16,32). f32 acc.
// ---------------------------------------------------------------------------

#define GATHER_GROUP(EPTR, EIDX)                                                \
    {                                                                           \
        int2 w_ = (EPTR)[EIDX];                                                 \
        uint4 g_ = tb4[(unsigned)w_.x * 8u + (unsigned)f];                      \
        float v_ = __int_as_float(w_.y);                                        \
        acc0 += v_ * __uint_as_float(g_.x << 16);                               \
        acc1 += v_ * __uint_as_float(g_.x & 0xFFFF0000u);                       \
        acc2 += v_ * __uint_as_float(g_.y << 16);                               \
        acc3 += v_ * __uint_as_float(g_.y & 0xFFFF0000u);                       \
        acc4 += v_ * __uint_as_float(g_.z << 16);                               \
        acc5 += v_ * __uint_as_float(g_.z & 0xFFFF0000u);                       \
        acc6 += v_ * __uint_as_float(g_.w << 16);                               \
        acc7 += v_ * __uint_as_float(g_.w & 0xFFFF0000u);                       \
    }

#define GATHER_CORE(TBL)                                                        \
    int el = lane >> 3;                                                         \
    int f  = lane & 7;                                                          \
    const uint4* tb4 = (const uint4*)(TBL);                                     \
    const int2* sp = spair + el;      /* octet edge pointer */                  \
    float acc0 = 0.f, acc1 = 0.f, acc2 = 0.f, acc3 = 0.f;                       \
    float acc4 = 0.f, acc5 = 0.f, acc6 = 0.f, acc7 = 0.f;                       \
    for (; e + 16 <= end; e += 16) {                                            \
        GATHER_GROUP(sp, e)                                                     \
        GATHER_GROUP(sp, e + 8)                                                 \
    }                                                                           \
    for (; e + 8 <= end; e += 8) {                                              \
        GATHER_GROUP(sp, e)                                                     \
    }                                                                           \
    if (e < end) {                                                              \
        int ei = e + el;                                                        \
        int ci = ei < end ? ei : end - 1;                                       \
        int2 w_ = spair[ci];                                                    \
        uint4 g_ = tb4[(unsigned)w_.x * 8u + (unsigned)f];                      \
        float v_ = (ei < end) ? __int_as_float(w_.y) : 0.f;                     \
        acc0 += v_ * __uint_as_float(g_.x << 16);                               \
        acc1 += v_ * __uint_as_float(g_.x & 0xFFFF0000u);                       \
        acc2 += v_ * __uint_as_float(g_.y << 16);                               \
        acc3 += v_ * __uint_as_float(g_.y & 0xFFFF0000u);                       \
        acc4 += v_ * __uint_as_float(g_.z << 16);                               \
        acc5 += v_ * __uint_as_float(g_.z & 0xFFFF0000u);                       \
        acc6 += v_ * __uint_as_float(g_.w << 16);                               \
        acc7 += v_ * __uint_as_float(g_.w & 0xFFFF0000u);                       \
    }                                                                           \
    acc0 += __shfl_xor(acc0, 8); acc0 += __shfl_xor(acc0, 16); acc0 += __shfl_xor(acc0, 32); \
    acc1 += __shfl_xor(acc1, 8); acc1 += __shfl_xor(acc1, 16); acc1 += __shfl_xor(acc1, 32); \
    acc2 += __shfl_xor(acc2, 8); acc2 += __shfl_xor(acc2, 16); acc2 += __shfl_xor(acc2, 32); \
    acc3 += __shfl_xor(acc3, 8); acc3 += __shfl_xor(acc3, 16); acc3 += __shfl_xor(acc3, 32); \
    acc4 += __shfl_xor(acc4, 8); acc4 += __shfl_xor(acc4, 16); acc4 += __shfl_xor(acc4, 32); \
    acc5 += __shfl_xor(acc5, 8); acc5 += __shfl_xor(acc5, 16); acc5 += __shfl_xor(acc5, 32); \
    acc6 += __shfl_xor(acc6, 8); acc6 += __shfl_xor(acc6, 16); acc6 += __shfl_xor(acc6, 32); \
    acc7 += __shfl_xor(acc7, 8); acc7 += __shfl_xor(acc7, 16); acc7 += __shfl_xor(acc7, 32);

__global__ void __launch_bounds__(256) spmm_gather1_kernel(
        const int2* __restrict__ oc, const int2* __restrict__ spair,
        const unsigned short* __restrict__ xb, unsigned short* __restrict__ axb, int N) {
    int wid = blockIdx.x * (blockDim.x >> 6) + (threadIdx.x >> 6);
    int lane = threadIdx.x & 63;
    if (wid >= N) return;
    int2 o = oc[wid];
    int e = o.x, end = o.x + o.y;
    GATHER_CORE(xb)
    if (el == 0) {
        uint4 pk;
        pk.x = (unsigned)f2bf(acc0) | ((unsigned)f2bf(acc1) << 16);
        pk.y = (unsigned)f2bf(acc2) | ((unsigned)f2bf(acc3) << 16);
        pk.z = (unsigned)f2bf(acc4) | ((unsigned)f2bf(acc5) << 16);
        pk.w = (unsigned)f2bf(acc6) | ((unsigned)f2bf(acc7) << 16);
        ((uint4*)axb)[(size_t)wid * 8 + f] = pk;
    }
}

__global__ void __launch_bounds__(256) spmm_gather2_kernel(
        const int2* __restrict__ oc, const int2* __restrict__ spair,
        const unsigned short* __restrict__ axb, const float* __restrict__ alpha,
        const float* __restrict__ x, float* __restrict__ out, int N) {
    int wid = blockIdx.x * (blockDim.x >> 6) + (threadIdx.x >> 6);
    int lane = threadIdx.x & 63;
    if (wid >= N) return;
    int2 o = oc[wid];
    int e = o.x, end = o.x + o.y;
    GATHER_CORE(axb)
    if (el == 0) {
        float a = 1.0f / (1.0f + __expf(-alpha[wid]));
        float4 xv0 = ((const float4*)x)[(size_t)wid * 16 + 2 * f];
        float4 xv1 = ((const float4*)x)[(size_t)wid * 16 + 2 * f + 1];
        float4 ov0, ov1;
        ov0.x = a * acc0 - xv0.x;
        ov0.y = a * acc1 - xv0.y;
        ov0.z = a * acc2 - xv0.z;
        ov0.w = a * acc3 - xv0.w;
        ov1.x = a * acc4 - xv1.x;
        ov1.y = a * acc5 - xv1.y;
        ov1.z = a * acc6 - xv1.z;
        ov1.w = a * acc7 - xv1.w;
        ((float4*)out)[(size_t)wid * 16 + 2 * f] = ov0;
        ((float4*)out)[(size_t)wid * 16 + 2 * f + 1] = ov1;
    }
}

// ---------------------------------------------------------------------------
// Fallback: atomic scatter path (if workspace too small)
// ---------------------------------------------------------------------------
__global__ void spmm_atomic_kernel(const int* __restrict__ rows, const int* __restrict__ cols,
                                   const float* __restrict__ vals, const float* __restrict__ x,
                                   float* __restrict__ y, int E) {
    long long tid = (long long)blockIdx.x * blockDim.x + threadIdx.x;
    long long total = (long long)E * 16;
    long long stride = (long long)gridDim.x * blockDim.x;
    for (; tid < total; tid += stride) {
        int e = (int)(tid >> 4);
        int q = (int)(tid & 15);
        int r = rows[e];
        int c = cols[e];
        float v = vals[e];
        float4 xv = reinterpret_cast<const float4*>(x)[(size_t)c * 16 + q];
        float* yp = y + (size_t)r * LATENT + q * 4;
        atomicAdd(yp + 0, v * xv.x);
        atomicAdd(yp + 1, v * xv.y);
        atomicAdd(yp + 2, v * xv.z);
        atomicAdd(yp + 3, v * xv.w);
    }
}

__global__ void finalize_kernel(const float* __restrict__ alpha, const float* __restrict__ x,
                                float* __restrict__ out, int N) {
    long long tid = (long long)blockIdx.x * blockDim.x + threadIdx.x;
    long long total = (long long)N * 16;
    long long stride = (long long)gridDim.x * blockDim.x;
    for (; tid < total; tid += stride) {
        int i = (int)(tid >> 4);
        float a = 1.0f / (1.0f + __expf(-alpha[i]));
        float4 ov = reinterpret_cast<float4*>(out)[tid];
        float4 xv = reinterpret_cast<const float4*>(x)[tid];
        ov.x = a * ov.x - xv.x;
        ov.y = a * ov.y - xv.y;
        ov.z = a * ov.z - xv.z;
        ov.w = a * ov.w - xv.w;
        reinterpret_cast<float4*>(out)[tid] = ov;
    }
}

// ---------------------------------------------------------------------------

extern "C" void kernel_launch(void* const* d_in, const int* in_sizes, int n_in,
                              void* d_out, int out_size, void* d_ws, size_t ws_size,
                              hipStream_t stream) {
    // setup_inputs order: t, x, alpha_train, edge_rows, edge_cols, edge_vals
    const float* x     = (const float*)d_in[1];
    const float* alpha = (const float*)d_in[2];
    const int*   rows  = (const int*)d_in[3];
    const int*   cols  = (const int*)d_in[4];
    const float* vals  = (const float*)d_in[5];

    const int N = in_sizes[2];   // 100000
    const int E = in_sizes[3];   // 3200000
    float* out = (float*)d_out;

    const int block = 256;
    const int nsub   = (N + SUB_ROWS - 1) >> SUB_SHIFT;   // 782
    const int ntiles = (E + TILE - 1) / TILE;             // 391

    auto align256 = [](size_t v) { return (v + 255) & ~(size_t)255; };

    // Region A: tmp (bin-sorted edges, alive through subsort), then reused
    // for xbf (bf16 x) + axbf (bf16 ax1).
    size_t tmp_bytes  = ((size_t)E + 8 * (size_t)nsub) * sizeof(int2);
    size_t xbf_bytes  = (size_t)N * LATENT * sizeof(unsigned short);
    size_t o_axbf_inA = align256(xbf_bytes);
    size_t bf_bytes   = o_axbf_inA + xbf_bytes;
    size_t RA = tmp_bytes > bf_bytes ? tmp_bytes : bf_bytes;

    size_t o_tmp    = 0;
    size_t o_spair  = align256(o_tmp + RA);
    size_t o_oc     = align256(o_spair + (size_t)E * sizeof(int2));
    size_t o_csr0   = align256(o_oc + (size_t)N * sizeof(int2));
    size_t o_tstart = align256(o_csr0 + (size_t)nsub * sizeof(int));
    size_t o_stot   = align256(o_tstart + (size_t)nsub * sizeof(int));
    size_t o_gcur   = align256(o_stot + (size_t)nsub * sizeof(int));
    size_t o_tot    = align256(o_gcur + (size_t)nsub * sizeof(int));
    size_t needed   = o_tot + (size_t)nsub * sizeof(int);
    size_t part_bytes = (size_t)HIST_BLOCKS * nsub * sizeof(int);

    if (ws_size >= needed && nsub <= NSUB_PAD && N <= (1 << COLBITS) &&
        part_bytes <= (size_t)E * sizeof(int2)) {
        char* ws = (char*)d_ws;
        int2*           tmp    = (int2*)(ws + o_tmp);
        unsigned short* xbf    = (unsigned short*)(ws + o_tmp);          // after subsort
        unsigned short* axbf   = (unsigned short*)(ws + o_tmp + o_axbf_inA);
        int2*           spair  = (int2*)(ws + o_spair);
        int*            part   = (int*)(ws + o_spair);   // aliases spair (earlier lifetime)
        int2*           oc     = (int2*)(ws + o_oc);
        int*            csr0   = (int*)(ws + o_csr0);
        int*            tstart = (int*)(ws + o_tstart);
        int*            stot   = (int*)(ws + o_stot);
        int*            gcur   = (int*)(ws + o_gcur);
        int*            tot    = (int*)(ws + o_tot);

        // CSR-bucket metadata
        subhist_kernel<<<HIST_BLOCKS, 256, 0, stream>>>(rows, part, E, nsub);
        reduce_partials_kernel<<<nsub, 256, 0, stream>>>(part, tot, nsub, HIST_BLOCKS);
        subscan_kernel<<<1, 256, 0, stream>>>(tot, csr0, tstart, stot, gcur, nsub);

        // Bin + sort edges into CSR order
        binscatter_kernel<<<ntiles, 512, 0, stream>>>(rows, cols, vals, gcur, tmp, E, nsub);
        subsort_kernel<<<nsub, 256, 0, stream>>>(tmp, tstart, stot, csr0, oc, spair, N);

        // tmp dead -> build bf16 x table in its region
        long long n4 = (long long)N * (LATENT / 4);
        conv_bf16_kernel<<<2048, 256, 0, stream>>>(x, xbf, n4);

        // Two gather hops (wave per row), 8 features/lane x 8 edge-slots
        int rows_per_block = block / 64;
        int grid_rows = (N + rows_per_block - 1) / rows_per_block;
        spmm_gather1_kernel<<<grid_rows, block, 0, stream>>>(oc, spair, xbf, axbf, N);
        spmm_gather2_kernel<<<grid_rows, block, 0, stream>>>(oc, spair, axbf,
                                                             alpha, x, out, N);
        return;
    }

    // Fallback: atomic scatter path
    {
        float* ax1 = (float*)d_ws;
        const size_t feat_bytes = (size_t)N * LATENT * sizeof(float);
        hipMemsetAsync(ax1, 0, feat_bytes, stream);
        hipMemsetAsync(out, 0, feat_bytes, stream);
        long long work = (long long)E * 16;
        int grid_spmm = (int)((work + block - 1) / block);
        spmm_atomic_kernel<<<grid_spmm, block, 0, stream>>>(rows, cols, vals, x, ax1, E);
        spmm_atomic_kernel<<<grid_spmm, block, 0, stream>>>(rows, cols, vals, ax1, out, E);
        long long fwork = (long long)N * 16;
        int grid_fin = (int)((fwork + block - 1) / block);
        finalize_kernel<<<grid_fin, block, 0, stream>>>(alpha, x, out, N);
    }
}

// Round 14
// 209.848 us; speedup vs baseline: 13.2540x; 1.0080x over previous
//
#include <hip/hip_runtime.h>

#define LATENT 64
#define SUB_SHIFT 7
#define SUB_ROWS 128
#define COLBITS 17
#define COL_MASK ((1 << COLBITS) - 1)
#define HIST_BLOCKS 256
#define TILE 8192
#define NSUB_PAD 1024

__device__ __forceinline__ unsigned short f2bf(float f) {
    unsigned u = __float_as_uint(f);
    unsigned r = (u + 0x7FFFu + ((u >> 16) & 1u)) >> 16;   // round-nearest-even
    return (unsigned short)r;
}

// ---------------------------------------------------------------------------
// Kernel A: per-block sub-bucket histogram partials (no global atomics)
// ---------------------------------------------------------------------------
__global__ void subhist_kernel(const int* __restrict__ rows, int* __restrict__ part,
                               int E, int nsub) {
    __shared__ int h[NSUB_PAD];
    int t = threadIdx.x;
    for (int i = t; i < NSUB_PAD; i += blockDim.x) h[i] = 0;
    __syncthreads();
    for (int e = blockIdx.x * blockDim.x + t; e < E; e += gridDim.x * blockDim.x)
        atomicAdd(&h[rows[e] >> SUB_SHIFT], 1);
    __syncthreads();
    for (int i = t; i < nsub; i += blockDim.x) part[blockIdx.x * nsub + i] = h[i];
}

// ---------------------------------------------------------------------------
// Kernel A2: parallel reduction of partials -> tot[s]. One block per sub-bucket.
// ---------------------------------------------------------------------------
__global__ void reduce_partials_kernel(const int* __restrict__ part, int* __restrict__ tot,
                                       int nsub, int nblk) {
    __shared__ int s[256];
    int sidx = blockIdx.x;
    int t = threadIdx.x;
    int acc = 0;
    for (int b = t; b < nblk; b += 256) acc += part[b * nsub + sidx];
    s[t] = acc;
    __syncthreads();
    for (int o = 128; o > 0; o >>= 1) {
        if (t < o) s[t] += s[t + o];
        __syncthreads();
    }
    if (t == 0) tot[sidx] = s[0];
}

// ---------------------------------------------------------------------------
// Kernel B (1 block): exclusive scan of tot -> csr0, tstart, stot, gcur
// ---------------------------------------------------------------------------
__global__ void subscan_kernel(const int* __restrict__ tot_in, int* __restrict__ csr0,
                               int* __restrict__ tstart, int* __restrict__ stot,
                               int* __restrict__ gcur, int nsub) {
    __shared__ int tot[NSUB_PAD];
    __shared__ int sc[256];
    int t = threadIdx.x;
    for (int i = t; i < NSUB_PAD; i += 256) tot[i] = (i < nsub) ? tot_in[i] : 0;
    __syncthreads();
    int c0 = tot[4 * t], c1 = tot[4 * t + 1], c2 = tot[4 * t + 2], c3 = tot[4 * t + 3];
    int csum = c0 + c1 + c2 + c3;
    sc[t] = csum;
    __syncthreads();
    for (int o = 1; o < 256; o <<= 1) {
        int u = (t >= o) ? sc[t - o] : 0;
        __syncthreads();
        sc[t] += u;
        __syncthreads();
    }
    int pre = sc[t] - csum;   // exclusive chunk base
    int s0 = 4 * t;
    if (s0 < nsub)     { csr0[s0] = pre;     stot[s0] = c0;     int ts = pre + 8 * s0;       tstart[s0] = ts;     gcur[s0] = ts; }
    pre += c0;
    if (s0 + 1 < nsub) { csr0[s0 + 1] = pre; stot[s0 + 1] = c1; int ts = pre + 8 * (s0 + 1); tstart[s0 + 1] = ts; gcur[s0 + 1] = ts; }
    pre += c1;
    if (s0 + 2 < nsub) { csr0[s0 + 2] = pre; stot[s0 + 2] = c2; int ts = pre + 8 * (s0 + 2); tstart[s0 + 2] = ts; gcur[s0 + 2] = ts; }
    pre += c2;
    if (s0 + 3 < nsub) { csr0[s0 + 3] = pre; stot[s0 + 3] = c3; int ts = pre + 8 * (s0 + 3); tstart[s0 + 3] = ts; gcur[s0 + 3] = ts; }
}

// ---------------------------------------------------------------------------
// f32 -> bf16 table, vectorized 4 at a time
// ---------------------------------------------------------------------------
__global__ void conv_bf16_kernel(const float* __restrict__ in,
                                 unsigned short* __restrict__ outb, long long n4) {
    long long i = (long long)blockIdx.x * blockDim.x + threadIdx.x;
    long long stride = (long long)gridDim.x * blockDim.x;
    for (; i < n4; i += stride) {
        float4 f = reinterpret_cast<const float4*>(in)[i];
        ushort4 o;
        o.x = f2bf(f.x); o.y = f2bf(f.y); o.z = f2bf(f.z); o.w = f2bf(f.w);
        reinterpret_cast<ushort4*>(outb)[i] = o;
    }
}

// ---------------------------------------------------------------------------
// Pass 1: tile-local LDS bucket sort, then append contiguous runs to bins.
// 512 threads (8 waves) with same 78KB LDS -> 16 waves/CU occupancy.
// ---------------------------------------------------------------------------
__global__ void __launch_bounds__(512, 2) binscatter_kernel(
        const int* __restrict__ rows, const int* __restrict__ cols,
        const float* __restrict__ vals, int* __restrict__ gcur,
        int2* __restrict__ tmp, int E, int nsub) {
    __shared__ int hist[NSUB_PAD];
    __shared__ int base[NSUB_PAD];
    __shared__ int gbase[NSUB_PAD];
    __shared__ int2 stage[TILE];
    __shared__ int sc[512];
    int t = threadIdx.x;
    int tb = blockIdx.x * TILE;
    int tilecnt = E - tb; if (tilecnt > TILE) tilecnt = TILE;

    for (int i = t; i < NSUB_PAD; i += 512) hist[i] = 0;
    __syncthreads();
    #pragma unroll
    for (int k = 0; k < TILE / 512; ++k) {
        int e = tb + k * 512 + t;
        if (e < E) atomicAdd(&hist[rows[e] >> SUB_SHIFT], 1);
    }
    __syncthreads();
    // exclusive scan over NSUB_PAD bins, chunk of 2 per thread
    int c0 = hist[2 * t], c1 = hist[2 * t + 1];
    int csum = c0 + c1;
    sc[t] = csum;
    __syncthreads();
    for (int o = 1; o < 512; o <<= 1) {
        int u = (t >= o) ? sc[t - o] : 0;
        __syncthreads();
        sc[t] += u;
        __syncthreads();
    }
    int ex = sc[t] - csum;
    base[2 * t] = ex;
    base[2 * t + 1] = ex + c0;
    __syncthreads();
    for (int i = t; i < NSUB_PAD; i += 512) hist[i] = 0;   // reset as cursors
    __syncthreads();
    #pragma unroll
    for (int k = 0; k < TILE / 512; ++k) {
        int e = tb + k * 512 + t;
        if (e < E) {
            int r = rows[e];
            int b = r >> SUB_SHIFT;
            int pos = base[b] + atomicAdd(&hist[b], 1);
            stage[pos] = make_int2(cols[e] | ((r & (SUB_ROWS - 1)) << COLBITS),
                                   __float_as_int(vals[e]));
        }
    }
    __syncthreads();
    for (int i = t; i < nsub; i += 512) {
        int n = hist[i];
        int gb = 0;
        if (n > 0) gb = atomicAdd(&gcur[i], n);
        gbase[i] = gb - base[i];
    }
    __syncthreads();
    for (int p = t; p < tilecnt; p += 512) {
        int lo = 0, hi = nsub;
        while (hi - lo > 1) { int mid = (lo + hi) >> 1; if (base[mid] <= p) lo = mid; else hi = mid; }
        tmp[gbase[lo] + p] = stage[p];
    }
}

// ---------------------------------------------------------------------------
// Pass 2: one block (512 threads) per sub-bucket -> offcnt, sorted spair.
// ---------------------------------------------------------------------------
__global__ void __launch_bounds__(512) subsort_kernel(
        const int2* __restrict__ tmp, const int* __restrict__ tstart,
        const int* __restrict__ stot, const int* __restrict__ csr0,
        int2* __restrict__ oc, int2* __restrict__ spair, int N) {
    __shared__ int lcnt[SUB_ROWS], lpos[SUB_ROWS], lcur[SUB_ROWS];
    int s = blockIdx.x;
    int t = threadIdx.x;
    int beg = tstart[s], n = stot[s], c0 = csr0[s];
    if (t < SUB_ROWS) lcnt[t] = 0;
    __syncthreads();
    for (int i = t; i < n; i += blockDim.x)
        atomicAdd(&lcnt[(tmp[beg + i].x >> COLBITS) & (SUB_ROWS - 1)], 1);
    __syncthreads();
    if (t < SUB_ROWS) lpos[t] = lcnt[t];
    __syncthreads();
    for (int o = 1; o < SUB_ROWS; o <<= 1) {
        int u = (t < SUB_ROWS && t >= o) ? lpos[t - o] : 0;
        __syncthreads();
        if (t < SUB_ROWS) lpos[t] += u;
        __syncthreads();
    }
    if (t < SUB_ROWS) {
        int excl = lpos[t] - lcnt[t];
        lcur[t] = excl;
        int row = (s << SUB_SHIFT) + t;
        if (row < N) oc[row] = make_int2(c0 + excl, lcnt[t]);
    }
    __syncthreads();
    for (int i = t; i < n; i += blockDim.x) {
        int2 w = tmp[beg + i];
        int rl = (w.x >> COLBITS) & (SUB_ROWS - 1);
        int p = atomicAdd(&lcur[rl], 1);
        spair[c0 + p] = make_int2(w.x & COL_MASK, w.y);
    }
}

// ---------------------------------------------------------------------------
// Gather hops: one wave per row; lane l -> features {8f..8f+7} (f=l&7) of
// edge-slot (l>>3). Per 8 edges: one int2 spair load + one 16B uint4 gather
// (1024B/instr = 8 full rows). Hot loop: 32 edges with all 4 gather chains
// issued before FMAs (4-deep MLP). Combine via shfl_xor(8,16,32). f32 acc.
// ---------------------------------------------------------------------------

#define FMA8(G, V)                                                              \
    acc0 += (V) * __uint_as_float((G).x << 16);                                 \
    acc1 += (V) * __uint_as_float((G).x & 0xFFFF0000u);                         \
    acc2 += (V) * __uint_as_float((G).y << 16);                                 \
    acc3 += (V) * __uint_as_float((G).y & 0xFFFF0000u);                         \
    acc4 += (V) * __uint_as_float((G).z << 16);                                 \
    acc5 += (V) * __uint_as_float((G).z & 0xFFFF0000u);                         \
    acc6 += (V) * __uint_as_float((G).w << 16);                                 \
    acc7 += (V) * __uint_as_float((G).w & 0xFFFF0000u);

#define GATHER_CORE(TBL)                                                        \
    int el = lane >> 3;                                                         \
    int f  = lane & 7;                                                          \
    const uint4* tb4 = (const uint4*)(TBL);                                     \
    const int2* sp = spair + el;      /* octet edge pointer */                  \
    float acc0 = 0.f, acc1 = 0.f, acc2 = 0.f, acc3 = 0.f;                       \
    float acc4 = 0.f, acc5 = 0.f, acc6 = 0.f, acc7 = 0.f;                       \
    for (; e + 32 <= end; e += 32) {                                            \
        int2 w0 = sp[e];      int2 w1 = sp[e + 8];                              \
        int2 w2 = sp[e + 16]; int2 w3 = sp[e + 24];                             \
        uint4 g0 = tb4[(unsigned)w0.x * 8u + (unsigned)f];                      \
        uint4 g1 = tb4[(unsigned)w1.x * 8u + (unsigned)f];                      \
        uint4 g2 = tb4[(unsigned)w2.x * 8u + (unsigned)f];                      \
        uint4 g3 = tb4[(unsigned)w3.x * 8u + (unsigned)f];                      \
        float v0 = __int_as_float(w0.y), v1 = __int_as_float(w1.y);             \
        float v2 = __int_as_float(w2.y), v3 = __int_as_float(w3.y);             \
        FMA8(g0, v0)                                                            \
        FMA8(g1, v1)                                                            \
        FMA8(g2, v2)                                                            \
        FMA8(g3, v3)                                                            \
    }                                                                           \
    for (; e + 8 <= end; e += 8) {                                              \
        int2 w_ = sp[e];                                                        \
        uint4 g_ = tb4[(unsigned)w_.x * 8u + (unsigned)f];                      \
        float v_ = __int_as_float(w_.y);                                        \
        FMA8(g_, v_)                                                            \
    }                                                                           \
    if (e < end) {                                                              \
        int ei = e + el;                                                        \
        int ci = ei < end ? ei : end - 1;                                       \
        int2 w_ = spair[ci];                                                    \
        uint4 g_ = tb4[(unsigned)w_.x * 8u + (unsigned)f];                      \
        float v_ = (ei < end) ? __int_as_float(w_.y) : 0.f;                     \
        FMA8(g_, v_)                                                            \
    }                                                                           \
    acc0 += __shfl_xor(acc0, 8); acc0 += __shfl_xor(acc0, 16); acc0 += __shfl_xor(acc0, 32); \
    acc1 += __shfl_xor(acc1, 8); acc1 += __shfl_xor(acc1, 16); acc1 += __shfl_xor(acc1, 32); \
    acc2 += __shfl_xor(acc2, 8); acc2 += __shfl_xor(acc2, 16); acc2 += __shfl_xor(acc2, 32); \
    acc3 += __shfl_xor(acc3, 8); acc3 += __shfl_xor(acc3, 16); acc3 += __shfl_xor(acc3, 32); \
    acc4 += __shfl_xor(acc4, 8); acc4 += __shfl_xor(acc4, 16); acc4 += __shfl_xor(acc4, 32); \
    acc5 += __shfl_xor(acc5, 8); acc5 += __shfl_xor(acc5, 16); acc5 += __shfl_xor(acc5, 32); \
    acc6 += __shfl_xor(acc6, 8); acc6 += __shfl_xor(acc6, 16); acc6 += __shfl_xor(acc6, 32); \
    acc7 += __shfl_xor(acc7, 8); acc7 += __shfl_xor(acc7, 16); acc7 += __shfl_xor(acc7, 32);

__global__ void __launch_bounds__(256) spmm_gather1_kernel(
        const int2* __restrict__ oc, const int2* __restrict__ spair,
        const unsigned short* __restrict__ xb, unsigned short* __restrict__ axb, int N) {
    int wid = blockIdx.x * (blockDim.x >> 6) + (threadIdx.x >> 6);
    int lane = threadIdx.x & 63;
    if (wid >= N) return;
    int2 o = oc[wid];
    int e = o.x, end = o.x + o.y;
    GATHER_CORE(xb)
    if (el == 0) {
        uint4 pk;
        pk.x = (unsigned)f2bf(acc0) | ((unsigned)f2bf(acc1) << 16);
        pk.y = (unsigned)f2bf(acc2) | ((unsigned)f2bf(acc3) << 16);
        pk.z = (unsigned)f2bf(acc4) | ((unsigned)f2bf(acc5) << 16);
        pk.w = (unsigned)f2bf(acc6) | ((unsigned)f2bf(acc7) << 16);
        ((uint4*)axb)[(size_t)wid * 8 + f] = pk;
    }
}

__global__ void __launch_bounds__(256) spmm_gather2_kernel(
        const int2* __restrict__ oc, const int2* __restrict__ spair,
        const unsigned short* __restrict__ axb, const float* __restrict__ alpha,
        const float* __restrict__ x, float* __restrict__ out, int N) {
    int wid = blockIdx.x * (blockDim.x >> 6) + (threadIdx.x >> 6);
    int lane = threadIdx.x & 63;
    if (wid >= N) return;
    int2 o = oc[wid];
    int e = o.x, end = o.x + o.y;
    GATHER_CORE(axb)
    if (el == 0) {
        float a = 1.0f / (1.0f + __expf(-alpha[wid]));
        float4 xv0 = ((const float4*)x)[(size_t)wid * 16 + 2 * f];
        float4 xv1 = ((const float4*)x)[(size_t)wid * 16 + 2 * f + 1];
        float4 ov0, ov1;
        ov0.x = a * acc0 - xv0.x;
        ov0.y = a * acc1 - xv0.y;
        ov0.z = a * acc2 - xv0.z;
        ov0.w = a * acc3 - xv0.w;
        ov1.x = a * acc4 - xv1.x;
        ov1.y = a * acc5 - xv1.y;
        ov1.z = a * acc6 - xv1.z;
        ov1.w = a * acc7 - xv1.w;
        ((float4*)out)[(size_t)wid * 16 + 2 * f] = ov0;
        ((float4*)out)[(size_t)wid * 16 + 2 * f + 1] = ov1;
    }
}

// ---------------------------------------------------------------------------
// Fallback: atomic scatter path (if workspace too small)
// ---------------------------------------------------------------------------
__global__ void spmm_atomic_kernel(const int* __restrict__ rows, const int* __restrict__ cols,
                                   const float* __restrict__ vals, const float* __restrict__ x,
                                   float* __restrict__ y, int E) {
    long long tid = (long long)blockIdx.x * blockDim.x + threadIdx.x;
    long long total = (long long)E * 16;
    long long stride = (long long)gridDim.x * blockDim.x;
    for (; tid < total; tid += stride) {
        int e = (int)(tid >> 4);
        int q = (int)(tid & 15);
        int r = rows[e];
        int c = cols[e];
        float v = vals[e];
        float4 xv = reinterpret_cast<const float4*>(x)[(size_t)c * 16 + q];
        float* yp = y + (size_t)r * LATENT + q * 4;
        atomicAdd(yp + 0, v * xv.x);
        atomicAdd(yp + 1, v * xv.y);
        atomicAdd(yp + 2, v * xv.z);
        atomicAdd(yp + 3, v * xv.w);
    }
}

__global__ void finalize_kernel(const float* __restrict__ alpha, const float* __restrict__ x,
                                float* __restrict__ out, int N) {
    long long tid = (long long)blockIdx.x * blockDim.x + threadIdx.x;
    long long total = (long long)N * 16;
    long long stride = (long long)gridDim.x * blockDim.x;
    for (; tid < total; tid += stride) {
        int i = (int)(tid >> 4);
        float a = 1.0f / (1.0f + __expf(-alpha[i]));
        float4 ov = reinterpret_cast<float4*>(out)[tid];
        float4 xv = reinterpret_cast<const float4*>(x)[tid];
        ov.x = a * ov.x - xv.x;
        ov.y = a * ov.y - xv.y;
        ov.z = a * ov.z - xv.z;
        ov.w = a * ov.w - xv.w;
        reinterpret_cast<float4*>(out)[tid] = ov;
    }
}

// ---------------------------------------------------------------------------

extern "C" void kernel_launch(void* const* d_in, const int* in_sizes, int n_in,
                              void* d_out, int out_size, void* d_ws, size_t ws_size,
                              hipStream_t stream) {
    // setup_inputs order: t, x, alpha_train, edge_rows, edge_cols, edge_vals
    const float* x     = (const float*)d_in[1];
    const float* alpha = (const float*)d_in[2];
    const int*   rows  = (const int*)d_in[3];
    const int*   cols  = (const int*)d_in[4];
    const float* vals  = (const float*)d_in[5];

    const int N = in_sizes[2];   // 100000
    const int E = in_sizes[3];   // 3200000
    float* out = (float*)d_out;

    const int block = 256;
    const int nsub   = (N + SUB_ROWS - 1) >> SUB_SHIFT;   // 782
    const int ntiles = (E + TILE - 1) / TILE;             // 391

    auto align256 = [](size_t v) { return (v + 255) & ~(size_t)255; };

    // Region A: tmp (bin-sorted edges, alive through subsort), then reused
    // for xbf (bf16 x) + axbf (bf16 ax1).
    size_t tmp_bytes  = ((size_t)E + 8 * (size_t)nsub) * sizeof(int2);
    size_t xbf_bytes  = (size_t)N * LATENT * sizeof(unsigned short);
    size_t o_axbf_inA = align256(xbf_bytes);
    size_t bf_bytes   = o_axbf_inA + xbf_bytes;
    size_t RA = tmp_bytes > bf_bytes ? tmp_bytes : bf_bytes;

    size_t o_tmp    = 0;
    size_t o_spair  = align256(o_tmp + RA);
    size_t o_oc     = align256(o_spair + (size_t)E * sizeof(int2));
    size_t o_csr0   = align256(o_oc + (size_t)N * sizeof(int2));
    size_t o_tstart = align256(o_csr0 + (size_t)nsub * sizeof(int));
    size_t o_stot   = align256(o_tstart + (size_t)nsub * sizeof(int));
    size_t o_gcur   = align256(o_stot + (size_t)nsub * sizeof(int));
    size_t o_tot    = align256(o_gcur + (size_t)nsub * sizeof(int));
    size_t needed   = o_tot + (size_t)nsub * sizeof(int);
    size_t part_bytes = (size_t)HIST_BLOCKS * nsub * sizeof(int);

    if (ws_size >= needed && nsub <= NSUB_PAD && N <= (1 << COLBITS) &&
        part_bytes <= (size_t)E * sizeof(int2)) {
        char* ws = (char*)d_ws;
        int2*           tmp    = (int2*)(ws + o_tmp);
        unsigned short* xbf    = (unsigned short*)(ws + o_tmp);          // after subsort
        unsigned short* axbf   = (unsigned short*)(ws + o_tmp + o_axbf_inA);
        int2*           spair  = (int2*)(ws + o_spair);
        int*            part   = (int*)(ws + o_spair);   // aliases spair (earlier lifetime)
        int2*           oc     = (int2*)(ws + o_oc);
        int*            csr0   = (int*)(ws + o_csr0);
        int*            tstart = (int*)(ws + o_tstart);
        int*            stot   = (int*)(ws + o_stot);
        int*            gcur   = (int*)(ws + o_gcur);
        int*            tot    = (int*)(ws + o_tot);

        // CSR-bucket metadata
        subhist_kernel<<<HIST_BLOCKS, 256, 0, stream>>>(rows, part, E, nsub);
        reduce_partials_kernel<<<nsub, 256, 0, stream>>>(part, tot, nsub, HIST_BLOCKS);
        subscan_kernel<<<1, 256, 0, stream>>>(tot, csr0, tstart, stot, gcur, nsub);

        // Bin + sort edges into CSR order
        binscatter_kernel<<<ntiles, 512, 0, stream>>>(rows, cols, vals, gcur, tmp, E, nsub);
        subsort_kernel<<<nsub, 512, 0, stream>>>(tmp, tstart, stot, csr0, oc, spair, N);

        // tmp dead -> build bf16 x table in its region
        long long n4 = (long long)N * (LATENT / 4);
        conv_bf16_kernel<<<2048, 256, 0, stream>>>(x, xbf, n4);

        // Two gather hops (wave per row), 8 features/lane x 8 edge-slots
        int rows_per_block = block / 64;
        int grid_rows = (N + rows_per_block - 1) / rows_per_block;
        spmm_gather1_kernel<<<grid_rows, block, 0, stream>>>(oc, spair, xbf, axbf, N);
        spmm_gather2_kernel<<<grid_rows, block, 0, stream>>>(oc, spair, axbf,
                                                             alpha, x, out, N);
        return;
    }

    // Fallback: atomic scatter path
    {
        float* ax1 = (float*)d_ws;
        const size_t feat_bytes = (size_t)N * LATENT * sizeof(float);
        hipMemsetAsync(ax1, 0, feat_bytes, stream);
        hipMemsetAsync(out, 0, feat_bytes, stream);
        long long work = (long long)E * 16;
        int grid_spmm = (int)((work + block - 1) / block);
        spmm_atomic_kernel<<<grid_spmm, block, 0, stream>>>(rows, cols, vals, x, ax1, E);
        spmm_atomic_kernel<<<grid_spmm, block, 0, stream>>>(rows, cols, vals, ax1, out, E);
        long long fwork = (long long)N * 16;
        int grid_fin = (int)((fwork + block - 1) / block);
        finalize_kernel<<<grid_fin, block, 0, stream>>>(alpha, x, out, N);
    }
}